// Round 6
// baseline (1308.637 us; speedup 1.0000x reference)
//
#include <hip/hip_runtime.h>
#include <math.h>

#define NEG_SLOPE 0.2f

typedef _Float16 half2_t __attribute__((ext_vector_type(2)));

__device__ __forceinline__ float lrelu(float x) {
    return fmaxf(x, NEG_SLOPE * x);
}

__device__ __forceinline__ float fdot2(half2_t a, half2_t b, float c) {
#if __has_builtin(__builtin_amdgcn_fdot2)
    return __builtin_amdgcn_fdot2(a, b, c, false);
#else
    return c + (float)a.x * (float)b.x + (float)a.y * (float)b.y;
#endif
}

__device__ __forceinline__ half2_t as_h2(uint u) {
    union { uint u; half2_t h; } c; c.u = u; return c.h;
}

constexpr int clog2(int n) { return (n <= 1) ? 0 : 1 + clog2(n / 2); }

// ---------------------------------------------------------------------------
// Layer 1 (fp32, CI=1). r6: weights staged to LDS (108 floats, 432 B).
// In-loop weight reads are ds_read_b32 at wave-uniform compile-time offsets
// -> HW broadcast, no VALU, no register pressure. This keeps r5's weight-
// path VALU reduction (-22% measured) WITHOUT r5's AGPR residency tax
// (22% occupancy = 2 waves/SIMD = the 256-reg/wave signature). Back to the
// (256,4) 64-VGPR tier, proven no-spill for the plane-wise structure (r2:
// WRITE_SIZE == output size exactly).
// ---------------------------------------------------------------------------
template<int CI, int CO, int S, int ZT, int PZT, int CPT, int BPB>
__global__ __launch_bounds__(256, 4) void conv_pool_f32h(
    const float* __restrict__ in,   // [B, CI, S,S,S]
    const float* __restrict__ w,    // [CO, CI, 3,3,3]
    const float* __restrict__ bias, // [CO]
    half2_t* __restrict__ out,      // [B, CO/2, SP^3] co-pair packed
    int B)
{
    constexpr int SP    = S / 2;
    constexpr int ZD    = 2 * ZT + 2;
    constexpr int YS    = S + 2;
    constexpr int XOFF  = 5;
    constexpr int XR    = S + 8;
    constexpr int PLANE = YS * XR;
    constexpr int NPAIR = BPB * CI * ZD;
    constexpr int LDS_N = NPAIR * PLANE;
    constexpr int NOG   = CO / CPT;
    constexpr int NZB   = ZT / PZT;
    constexpr int NPOS  = NZB * SP * SP;
    constexpr int NSLAB = SP / ZT;
    constexpr int NW    = CO * CI * 27;
    static_assert(BPB * NOG * NPOS == 256, "thread mapping must cover block");
    static_assert((LDS_N & 3) == 0, "float4 zero");
    static_assert((CPT & 1) == 0, "pack pairs");
    static_assert(NW <= 256, "weight stage in one pass");

    __shared__ __align__(16) float sm[LDS_N];
    __shared__ float wsm[NW];

    const int t     = threadIdx.x;
    const int zslab = blockIdx.x & (NSLAB - 1);
    const int b0    = (blockIdx.x >> clog2(NSLAB)) * BPB;
    const int zp0   = zslab * ZT;
    const int gz0   = 2 * zp0 - 1;

    {   // Phase A: zero LDS
        float4* s4 = (float4*)sm;
        constexpr int N4 = LDS_N / 4;
#pragma unroll
        for (int i = 0; i < (N4 + 255) / 256; ++i) {
            const int k = t + i * 256;
            if (k < N4) s4[k] = make_float4(0.f, 0.f, 0.f, 0.f);
        }
    }
    __syncthreads();

    {   // Phase B: interior rows, float4 loads
        constexpr int CHUNKS = S / 4;
        constexpr int PJOBS  = S * CHUNKS;
        constexpr int PPI    = 256 / PJOBS;
        constexpr int FITER  = NPAIR / PPI;
        static_assert(FITER * PPI == NPAIR, "fill covers planes exactly");
        const int idx  = t & (PJOBS - 1);
        const int poff = t >> clog2(PJOBS);
        const int cc   = idx & (CHUNKS - 1);
        const int yy   = idx >> clog2(CHUNKS);
#pragma unroll
        for (int it = 0; it < FITER; ++it) {
            const int plane = it * PPI + poff;
            const int z     = plane % ZD;
            const int bci   = plane / ZD;
            const int gz    = gz0 + z;
            if ((unsigned)gz < (unsigned)S) {
                const float4 v = *(const float4*)&in[
                    ((long)(b0 * CI + bci) * S + gz) * (S * S) + yy * S + 4 * cc];
                float* sp = &sm[(plane * YS + (yy + 1)) * XR + XOFF + 4 * cc];
                sp[0] = v.x; sp[1] = v.y; sp[2] = v.z; sp[3] = v.w;
            }
        }
    }

    // stage weights to LDS (broadcast-read in the FMA loop)
    if (t < NW) wsm[t] = w[t];

    __syncthreads();

    const int pos = t & (NPOS - 1);
    const int og  = __builtin_amdgcn_readfirstlane(
                        (t >> clog2(NPOS)) & (NOG - 1));      // wave-uniform
    const int bl  = __builtin_amdgcn_readfirstlane(
                        t >> clog2(NPOS * NOG));              // wave-uniform
    const int xp  = pos & (SP - 1);
    const int yp  = (pos >> clog2(SP)) & (SP - 1);
    const int zb  = pos >> (2 * clog2(SP));

#pragma unroll
    for (int zi = 0; zi < PZT; ++zi) {
        const int zl = zb * PZT + zi;
        float acc[CPT][8];
#pragma unroll
        for (int oo = 0; oo < CPT; ++oo)
#pragma unroll
            for (int p = 0; p < 8; ++p) acc[oo][p] = 0.f;

#pragma unroll 1
        for (int ci = 0; ci < CI; ++ci) {
            const float* sp_ = &sm[((bl * CI + ci) * ZD + 2 * zl) * PLANE +
                                   (2 * yp) * XR + 2 * xp + (XOFF - 1)]; // even
#pragma unroll
            for (int dz = 0; dz < 4; ++dz) {
                float v[4][4];
#pragma unroll
                for (int dy = 0; dy < 4; ++dy) {
                    const float2 q0 = *(const float2*)&sp_[dz * PLANE + dy * XR];
                    const float2 q1 = *(const float2*)&sp_[dz * PLANE + dy * XR + 2];
                    v[dy][0] = q0.x; v[dy][1] = q0.y;
                    v[dy][2] = q1.x; v[dy][3] = q1.y;
                }
#pragma unroll
                for (int kz = 0; kz < 3; ++kz) {
                    const int pz = dz - kz;
                    if (pz >= 0 && pz < 2) {
#pragma unroll
                        for (int oo = 0; oo < CPT; ++oo) {
#pragma unroll
                            for (int ky = 0; ky < 3; ++ky)
#pragma unroll
                                for (int kx = 0; kx < 3; ++kx) {
                                    const float wv = wsm[
                                        ((og * CPT + oo) * CI + ci) * 27 +
                                        kz * 9 + ky * 3 + kx];
#pragma unroll
                                    for (int py = 0; py < 2; ++py)
#pragma unroll
                                        for (int px = 0; px < 2; ++px)
                                            acc[oo][pz * 4 + py * 2 + px] +=
                                                v[py + ky][px + kx] * wv;
                                }
                        }
                    }
                }
            }
        }

#pragma unroll
        for (int oo = 0; oo < CPT; oo += 2) {
            const int o = og * CPT + oo;
            float m0 = acc[oo][0], m1 = acc[oo + 1][0];
#pragma unroll
            for (int p = 1; p < 8; ++p) {
                m0 = fmaxf(m0, acc[oo][p]);
                m1 = fmaxf(m1, acc[oo + 1][p]);
            }
            half2_t hv;
            hv.x = (_Float16)lrelu(m0 + bias[o]);
            hv.y = (_Float16)lrelu(m1 + bias[o + 1]);
            out[(long)((b0 + bl) * (CO / 2) + (o >> 1)) * (SP * SP * SP) +
                ((zp0 + zl) * SP + yp) * SP + xp] = hv;
        }
    }
}

// ---------------------------------------------------------------------------
// Layer 2 (r4/r5 config, kept): BPB=1, CPT=2, 19KB LDS -> 8 blk/CU,
// merged-zi sweep (acc[2][2][8]=32 regs, each plane read once).
// ---------------------------------------------------------------------------
template<int CIH, int CO, int S, int ZT, int PZT, int CPT, int BPB>
__global__ __launch_bounds__(256, 6) void conv_pool_h2(
    const half2_t* __restrict__ in,  // [B, CIH, S,S,S]
    const uint*   __restrict__ wh,   // [CO, CIH, 27] packed pairs
    const float*  __restrict__ bias, // [CO]
    half2_t* __restrict__ out,       // [B, CO/2, SP^3]
    int B)
{
    constexpr int SP    = S / 2;
    constexpr int ZD    = 2 * ZT + 2;
    constexpr int YS    = S + 2;
    constexpr int XOFF  = 3;
    constexpr int XR    = S + 6;
    constexpr int PLANE = YS * XR;
    constexpr int NPAIR = BPB * CIH * ZD;
    constexpr int LDS_N = NPAIR * PLANE;
    constexpr int NOG   = CO / CPT;
    constexpr int NZB   = ZT / PZT;
    constexpr int NPOS  = NZB * SP * SP;
    constexpr int NSLAB = SP / ZT;
    static_assert(BPB * NOG * NPOS == 256, "thread mapping must cover block");
    static_assert((LDS_N & 3) == 0, "uint4 zero");
    static_assert((CPT & 1) == 0, "pack pairs");

    __shared__ __align__(16) uint sm[LDS_N];
    const uint* inu = (const uint*)in;

    const int t     = threadIdx.x;
    const int zslab = blockIdx.x & (NSLAB - 1);
    const int b0    = (blockIdx.x >> clog2(NSLAB)) * BPB;
    const int zp0   = zslab * ZT;
    const int gz0   = 2 * zp0 - 1;

    {   // Phase A: zero LDS
        uint4* s4 = (uint4*)sm;
        constexpr int N4 = LDS_N / 4;
#pragma unroll
        for (int i = 0; i < (N4 + 255) / 256; ++i) {
            const int k = t + i * 256;
            if (k < N4) s4[k] = make_uint4(0, 0, 0, 0);
        }
    }
    __syncthreads();

    {   // Phase B: interior rows, uint2 global loads
        constexpr int CH    = S / 2;
        constexpr int PJOBS = S * CH;
        constexpr int ITERS = NPAIR * PJOBS / 256;
        static_assert(ITERS * 256 == NPAIR * PJOBS, "exact fill");
#pragma unroll
        for (int it = 0; it < ITERS; ++it) {
            const int i     = t + it * 256;
            const int idx   = i & (PJOBS - 1);
            const int plane = i >> clog2(PJOBS);
            const int cc    = idx & (CH - 1);
            const int yy    = idx >> clog2(CH);
            const int z     = plane % ZD;
            const int bci   = plane / ZD;
            const int gz    = gz0 + z;
            if ((unsigned)gz < (unsigned)S) {
                const uint2 v = *(const uint2*)&inu[
                    ((long)(b0 * CIH + bci) * S + gz) * (S * S) + yy * S + 2 * cc];
                uint* sp = &sm[(plane * YS + yy + 1) * XR + XOFF + 2 * cc];
                sp[0] = v.x; sp[1] = v.y;
            }
        }
    }
    __syncthreads();

    const int pos = t & (NPOS - 1);
    const int og  = __builtin_amdgcn_readfirstlane(
                        (t >> clog2(NPOS)) & (NOG - 1));       // wave-uniform
    const int bl  = __builtin_amdgcn_readfirstlane(
                        t >> clog2(NPOS * NOG));               // wave-uniform
    const int xp  = pos & (SP - 1);
    const int yp  = (pos >> clog2(SP)) & (SP - 1);
    const int zb  = pos >> (2 * clog2(SP));

    float acc[PZT][CPT][8];
#pragma unroll
    for (int zi = 0; zi < PZT; ++zi)
#pragma unroll
        for (int oo = 0; oo < CPT; ++oo)
#pragma unroll
            for (int p = 0; p < 8; ++p) acc[zi][oo][p] = 0.f;

#pragma unroll 1
    for (int cp = 0; cp < CIH; ++cp) {
        const uint* sp_ = &sm[((bl * CIH + cp) * ZD + 2 * zb * PZT) * PLANE +
                              (2 * yp) * XR + 2 * xp + (XOFF - 1)]; // even
#pragma unroll
        for (int dz = 0; dz < 2 * PZT + 2; ++dz) {
            half2_t v[4][4];
#pragma unroll
            for (int dy = 0; dy < 4; ++dy) {
                const uint2 q0 = *(const uint2*)&sp_[dz * PLANE + dy * XR];
                const uint2 q1 = *(const uint2*)&sp_[dz * PLANE + dy * XR + 2];
                v[dy][0] = as_h2(q0.x); v[dy][1] = as_h2(q0.y);
                v[dy][2] = as_h2(q1.x); v[dy][3] = as_h2(q1.y);
            }
#pragma unroll
            for (int zi = 0; zi < PZT; ++zi) {
                const int dzl = dz - 2 * zi;
                if (dzl >= 0 && dzl < 4) {
#pragma unroll
                    for (int kz = 0; kz < 3; ++kz) {
                        const int pz = dzl - kz;
                        if (pz >= 0 && pz < 2) {
#pragma unroll
                            for (int oo = 0; oo < CPT; ++oo) {
                                const uint* wp = wh +
                                    (long)((og * CPT + oo) * CIH + cp) * 27 + kz * 9;
#pragma unroll
                                for (int ky = 0; ky < 3; ++ky)
#pragma unroll
                                    for (int kx = 0; kx < 3; ++kx) {
                                        const half2_t wv = as_h2(wp[ky * 3 + kx]);
#pragma unroll
                                        for (int py = 0; py < 2; ++py)
#pragma unroll
                                            for (int px = 0; px < 2; ++px)
                                                acc[zi][oo][pz * 4 + py * 2 + px] =
                                                    fdot2(v[py + ky][px + kx], wv,
                                                          acc[zi][oo][pz * 4 + py * 2 + px]);
                                    }
                            }
                        }
                    }
                }
            }
        }
    }

#pragma unroll
    for (int zi = 0; zi < PZT; ++zi) {
        const int zl = zb * PZT + zi;
#pragma unroll
        for (int oo = 0; oo < CPT; oo += 2) {
            const int o = og * CPT + oo;
            float m0 = acc[zi][oo][0], m1 = acc[zi][oo + 1][0];
#pragma unroll
            for (int p = 1; p < 8; ++p) {
                m0 = fmaxf(m0, acc[zi][oo][p]);
                m1 = fmaxf(m1, acc[zi][oo + 1][p]);
            }
            half2_t hv;
            hv.x = (_Float16)lrelu(m0 + bias[o]);
            hv.y = (_Float16)lrelu(m1 + bias[o + 1]);
            out[(long)((b0 + bl) * (CO / 2) + (o >> 1)) * (SP * SP * SP) +
                ((zp0 + zl) * SP + yp) * SP + xp] = hv;
        }
    }
}

// ---------------------------------------------------------------------------
// Fused tail (unchanged from r3/r4/r5 passing builds).
// ---------------------------------------------------------------------------
__global__ __launch_bounds__(256, 4) void tail_fused2(
    const uint*  __restrict__ in,   // buf2h [B][4][8^3] half2 words
    const uint*  __restrict__ wh3,  // [16][4][27]
    const uint*  __restrict__ wh4,  // [32][8][27]
    const uint*  __restrict__ wh5,  // [64][16][27]
    const float* __restrict__ cb3, const float* __restrict__ cb4,
    const float* __restrict__ cb5,
    const float* __restrict__ W1, const float* __restrict__ fb1,
    const float* __restrict__ W2, const float* __restrict__ fb2,
    const float* __restrict__ W3, const float* __restrict__ fb3,
    float* __restrict__ out)        // [B,6,4]
{
    constexpr int S3IN  = 0;
    constexpr int S3OUT = 4800;
    constexpr int S4OUT = 6528;
    constexpr int FEAT  = 7552;
    constexpr int H1O   = 7616;
    constexpr int H2O   = 7808;
    constexpr int H3O   = 7904;
    constexpr int LDS_N = 7936;

    __shared__ __align__(16) uint sm[LDS_N];
    float* smf = (float*)sm;
    _Float16* s3h = (_Float16*)(sm + S3OUT);
    _Float16* s4h = (_Float16*)(sm + S4OUT);

    const int t = threadIdx.x;
    const int b = blockIdx.x;

    {
        uint4* s4 = (uint4*)sm;
#pragma unroll
        for (int i = 0; i < 8; ++i) {
            const int k = t + i * 256;
            if (k < LDS_N / 4) s4[k] = make_uint4(0, 0, 0, 0);
        }
    }
    __syncthreads();

#pragma unroll
    for (int it = 0; it < 4; ++it) {
        const int i  = t + it * 256;
        const int xc = i & 3;
        const int yy = (i >> 2) & 7;
        const int zz = (i >> 5) & 7;
        const int cp = i >> 8;
        const uint2 v = *(const uint2*)&in[
            ((long)b * 4 + cp) * 512 + (zz * 8 + yy) * 8 + 2 * xc];
        uint* sp = &sm[S3IN + cp * 1200 + (zz + 1) * 120 + (yy + 1) * 12 +
                       3 + 2 * xc];
        sp[0] = v.x; sp[1] = v.y;
    }
    __syncthreads();

    // ---- L3: pos64 x cog4 (wave-uniform), 4 co per thread ----
    {
        const int pos = t & 63;
        const int cog = __builtin_amdgcn_readfirstlane(t >> 6);
        const int xp = pos & 3;
        const int yp = (pos >> 2) & 3;
        const int zp = pos >> 4;

        float acc[4][8];
#pragma unroll
        for (int oo = 0; oo < 4; ++oo)
#pragma unroll
            for (int p = 0; p < 8; ++p) acc[oo][p] = 0.f;

#pragma unroll 1
        for (int cp = 0; cp < 4; ++cp) {
            const uint* base = &sm[S3IN + cp * 1200 + 2 * zp * 120 +
                                   2 * yp * 12 + 2 * xp + 2];
#pragma unroll
            for (int dz = 0; dz < 4; ++dz) {
                half2_t v[4][4];
#pragma unroll
                for (int dy = 0; dy < 4; ++dy) {
                    const uint2 q0 = *(const uint2*)&base[dz * 120 + dy * 12];
                    const uint2 q1 = *(const uint2*)&base[dz * 120 + dy * 12 + 2];
                    v[dy][0] = as_h2(q0.x); v[dy][1] = as_h2(q0.y);
                    v[dy][2] = as_h2(q1.x); v[dy][3] = as_h2(q1.y);
                }
#pragma unroll
                for (int kz = 0; kz < 3; ++kz) {
                    const int pz = dz - kz;
                    if (pz >= 0 && pz < 2) {
#pragma unroll
                        for (int oo = 0; oo < 4; ++oo) {
                            const uint* wp = &wh3[((cog * 4 + oo) * 4 + cp) * 27 +
                                                  kz * 9];
#pragma unroll
                            for (int ky = 0; ky < 3; ++ky)
#pragma unroll
                                for (int kx = 0; kx < 3; ++kx) {
                                    const half2_t wv = as_h2(wp[ky * 3 + kx]);
#pragma unroll
                                    for (int py = 0; py < 2; ++py)
#pragma unroll
                                        for (int px = 0; px < 2; ++px)
                                            acc[oo][pz * 4 + py * 2 + px] =
                                                fdot2(v[py + ky][px + kx], wv,
                                                      acc[oo][pz * 4 + py * 2 + px]);
                                }
                        }
                    }
                }
            }
        }
        const int hbase = (((zp + 1) * 6 + (yp + 1)) * 6 + (xp + 1)) << 4;
#pragma unroll
        for (int oo = 0; oo < 4; ++oo) {
            const int co = cog * 4 + oo;
            float m = acc[oo][0];
#pragma unroll
            for (int p = 1; p < 8; ++p) m = fmaxf(m, acc[oo][p]);
            s3h[hbase + co] = (_Float16)lrelu(m + cb3[co]);
        }
    }
    __syncthreads();

    // ---- L4: pos8 x co32 ----
    {
        const int co = t >> 3;
        const int pos = t & 7;
        const int xp = pos & 1;
        const int yp = (pos >> 1) & 1;
        const int zp = pos >> 2;
        const uint* vbase = &sm[S3OUT + (((2 * zp * 6 + 2 * yp) * 6 + 2 * xp) << 3)];
        float acc[8];
#pragma unroll
        for (int p = 0; p < 8; ++p) acc[p] = 0.f;
#pragma unroll 1
        for (int c = 0; c < 8; ++c) {
            const uint* wp = &wh4[(co * 8 + c) * 27];
#pragma unroll
            for (int dz = 0; dz < 4; ++dz) {
                half2_t v[4][4];
#pragma unroll
                for (int dy = 0; dy < 4; ++dy)
#pragma unroll
                    for (int dx = 0; dx < 4; ++dx)
                        v[dy][dx] = as_h2(vbase[(((dz * 6 + dy) * 6 + dx) << 3) + c]);
#pragma unroll
                for (int kz = 0; kz < 3; ++kz) {
                    const int pz = dz - kz;
                    if (pz >= 0 && pz < 2) {
#pragma unroll
                        for (int ky = 0; ky < 3; ++ky)
#pragma unroll
                            for (int kx = 0; kx < 3; ++kx) {
                                const half2_t wv = as_h2(wp[kz * 9 + ky * 3 + kx]);
#pragma unroll
                                for (int py = 0; py < 2; ++py)
#pragma unroll
                                    for (int px = 0; px < 2; ++px)
                                        acc[pz * 4 + py * 2 + px] =
                                            fdot2(v[py + ky][px + kx], wv,
                                                  acc[pz * 4 + py * 2 + px]);
                            }
                    }
                }
            }
        }
        float m = acc[0];
#pragma unroll
        for (int p = 1; p < 8; ++p) m = fmaxf(m, acc[p]);
        s4h[((((zp + 1) * 4 + (yp + 1)) * 4 + (xp + 1)) << 5) + co] =
            (_Float16)lrelu(m + cb4[co]);
    }
    __syncthreads();

    // ---- L5: co64 x cq4 partials ----
    {
        const int co = t & 63;
        const int cq = __builtin_amdgcn_readfirstlane(t >> 6);
        float acc[8];
#pragma unroll
        for (int p = 0; p < 8; ++p) acc[p] = 0.f;
#pragma unroll 1
        for (int ci = 0; ci < 4; ++ci) {
            const int c = cq * 4 + ci;
            const uint* wp = &wh5[(co * 16 + c) * 27];
#pragma unroll
            for (int dz = 0; dz < 4; ++dz) {
                half2_t v[4][4];
#pragma unroll
                for (int dy = 0; dy < 4; ++dy)
#pragma unroll
                    for (int dx = 0; dx < 4; ++dx)
                        v[dy][dx] = as_h2(sm[S4OUT +
                            (((dz * 4 + dy) * 4 + dx) << 4) + c]);
#pragma unroll
                for (int kz = 0; kz < 3; ++kz) {
                    const int pz = dz - kz;
                    if (pz >= 0 && pz < 2) {
#pragma unroll
                        for (int ky = 0; ky < 3; ++ky)
#pragma unroll
                            for (int kx = 0; kx < 3; ++kx) {
                                const half2_t wv = as_h2(wp[kz * 9 + ky * 3 + kx]);
#pragma unroll
                                for (int py = 0; py < 2; ++py)
#pragma unroll
                                    for (int px = 0; px < 2; ++px)
                                        acc[pz * 4 + py * 2 + px] =
                                            fdot2(v[py + ky][px + kx], wv,
                                                  acc[pz * 4 + py * 2 + px]);
                            }
                    }
                }
            }
        }
#pragma unroll
        for (int p = 0; p < 8; ++p)
            smf[(cq * 64 + co) * 9 + p] = acc[p];
    }
    __syncthreads();

    if (t < 64) {
        float acc[8];
#pragma unroll
        for (int p = 0; p < 8; ++p)
            acc[p] = smf[t * 9 + p] + smf[(64 + t) * 9 + p] +
                     smf[(128 + t) * 9 + p] + smf[(192 + t) * 9 + p];
        float m = acc[0];
#pragma unroll
        for (int p = 1; p < 8; ++p) m = fmaxf(m, acc[p]);
        smf[FEAT + t] = lrelu(m + cb5[t]);
    }
    __syncthreads();

    if (t < 192) {
        const int j = t & 31;
        const int h = t >> 5;
        float s = fb1[h * 32 + j];
#pragma unroll
        for (int k = 0; k < 64; ++k)
            s += smf[FEAT + k] * W1[(h * 64 + k) * 32 + j];
        smf[H1O + h * 32 + j] = lrelu(s);
    }
    __syncthreads();

    if (t < 96) {
        const int j = t & 15;
        const int h = t >> 4;
        float s = fb2[h * 16 + j];
#pragma unroll
        for (int k = 0; k < 32; ++k)
            s += smf[H1O + h * 32 + k] * W2[(h * 32 + k) * 16 + j];
        smf[H2O + h * 16 + j] = lrelu(s);
    }
    __syncthreads();

    if (t < 24) {
        const int j = t & 3;
        const int h = t >> 2;
        float s = fb3[h * 4 + j];
#pragma unroll
        for (int k = 0; k < 16; ++k)
            s += smf[H2O + h * 16 + k] * W3[(h * 16 + k) * 4 + j];
        smf[H3O + h * 4 + j] = lrelu(s);
    }
    __syncthreads();

    if (t < 24) {
        const int q = t & 3;
        const int h = t >> 2;
        const float x0 = smf[H3O + h * 4 + 0];
        const float x1 = smf[H3O + h * 4 + 1];
        const float x2 = smf[H3O + h * 4 + 2];
        const float x3 = smf[H3O + h * 4 + 3];
        const float inv = 1.f / sqrtf(x0 * x0 + x1 * x1 + x2 * x2 + x3 * x3);
        out[(b * 6 + h) * 4 + q] = smf[H3O + h * 4 + q] * inv;
    }
}

// ---------------------------------------------------------------------------
// Weight pre-pack: fp32 [CO][CI][27] -> half2 [CO][CI/2][27] (pairs over ci).
// ---------------------------------------------------------------------------
__device__ __forceinline__ void pack_one(int i, const float* w, uint* h,
                                         int CO, int CI)
{
    const int CIH = CI / 2;
    const int n = CO * CIH * 27;
    if (i < n) {
        const int tap = i % 27;
        const int r   = i / 27;
        const int cp  = r % CIH;
        const int co  = r / CIH;
        const float* s = w + ((co * CI + 2 * cp) * 27 + tap);
        union { uint u; half2_t v; } c;
        c.v.x = (_Float16)s[0];
        c.v.y = (_Float16)s[27];
        h[i] = c.u;
    }
}

__global__ __launch_bounds__(256) void pack_weights(
    const float* w2, const float* w3, const float* w4, const float* w5,
    uint* h2, uint* h3, uint* h4, uint* h5)
{
    const int i = blockIdx.x * 256 + threadIdx.x;
    pack_one(i, w2, h2, 8, 4);
    pack_one(i, w3, h3, 16, 8);
    pack_one(i, w4, h4, 32, 16);
    pack_one(i, w5, h5, 64, 32);
}

extern "C" void kernel_launch(void* const* d_in, const int* in_sizes, int n_in,
                              void* d_out, int out_size, void* d_ws, size_t ws_size,
                              hipStream_t stream)
{
    const float* voxel = (const float*)d_in[0];
    const float* cw1 = (const float*)d_in[1];  const float* cb1 = (const float*)d_in[2];
    const float* cw2 = (const float*)d_in[3];  const float* cb2 = (const float*)d_in[4];
    const float* cw3 = (const float*)d_in[5];  const float* cb3 = (const float*)d_in[6];
    const float* cw4 = (const float*)d_in[7];  const float* cb4 = (const float*)d_in[8];
    const float* cw5 = (const float*)d_in[9];  const float* cb5 = (const float*)d_in[10];
    const float* W1  = (const float*)d_in[11]; const float* b1  = (const float*)d_in[12];
    const float* W2  = (const float*)d_in[13]; const float* b2  = (const float*)d_in[14];
    const float* W3  = (const float*)d_in[15]; const float* b3  = (const float*)d_in[16];
    float* out = (float*)d_out;

    const int B = 1024;
    uint* buf1h = (uint*)d_ws;                 // [1024][2][16^3]  8388608 w
    uint* buf2h = buf1h + 8388608;             // [1024][4][8^3]   2097152 w
    uint* wh2   = buf2h + 2097152;             // 432
    uint* wh3   = wh2 + 432;                   // 1728
    uint* wh4   = wh3 + 1728;                  // 6912
    uint* wh5   = wh4 + 6912;                  // 27648

    pack_weights<<<108, 256, 0, stream>>>(cw2, cw3, cw4, cw5, wh2, wh3, wh4, wh5);

    // L1: 1->4, 32^3->16^3 (fp32, plane-wise, LDS-broadcast weights)
    conv_pool_f32h<1, 4, 32, 2, 2, 4, 1><<<1024 * 8, 256, 0, stream>>>(
        voxel, cw1, cb1, (half2_t*)buf1h, B);
    // L2: CIH=2, 16^3->8^3 (dot2, BPB=1 CPT=2: 19KB LDS, 8 blk/CU, merged-zi)
    conv_pool_h2<2, 8, 16, 2, 2, 2, 1><<<1024 * 4, 256, 0, stream>>>(
        (const half2_t*)buf1h, wh2, cb2, (half2_t*)buf2h, B);
    // L3+L4+L5+FC fused: 1 batch/block (unchanged)
    tail_fused2<<<1024, 256, 0, stream>>>(
        buf2h, wh3, wh4, wh5, cb3, cb4, cb5,
        W1, b1, W2, b2, W3, b3, out);
}

// Round 7
// 424.548 us; speedup vs baseline: 3.0824x; 3.0824x over previous
//
#include <hip/hip_runtime.h>
#include <math.h>

#define NEG_SLOPE 0.2f

typedef _Float16 half2_t __attribute__((ext_vector_type(2)));

__device__ __forceinline__ float lrelu(float x) {
    return fmaxf(x, NEG_SLOPE * x);
}

__device__ __forceinline__ float fdot2(half2_t a, half2_t b, float c) {
#if __has_builtin(__builtin_amdgcn_fdot2)
    return __builtin_amdgcn_fdot2(a, b, c, false);
#else
    return c + (float)a.x * (float)b.x + (float)a.y * (float)b.y;
#endif
}

__device__ __forceinline__ half2_t as_h2(uint u) {
    union { uint u; half2_t h; } c; c.u = u; return c.h;
}

constexpr int clog2(int n) { return (n <= 1) ? 0 : 1 + clog2(n / 2); }

// ---------------------------------------------------------------------------
// Layer 1 (fp32, CI=1). r7: CO-PAIR SPLIT PASSES.
// Cross-round VALU arithmetic shows acc[4][8] has been living in AGPRs all
// along (r2: 5660 VALU/wave = 1728 FMA x3 -> accvgpr_read+fmac+accvgpr_write
// per FMA). Fix the DEMAND, not the placement: compute 2 co at a time
// (acc[2][8]=16 regs + one 4x4 plane=16 -> ~45 live, inside 64 arch VGPRs
// with scheduler headroom). LDS plane reads double (LDS pipe has ~6x
// headroom). All reduction orders unchanged -> bitwise identical output.
// unroll-1 on zi/oh/ci denies the scheduler its pressure-inflating batching.
// ---------------------------------------------------------------------------
template<int CI, int CO, int S, int ZT, int PZT, int CPT, int BPB>
__global__ __launch_bounds__(256, 4) void conv_pool_f32h(
    const float* __restrict__ in,   // [B, CI, S,S,S]
    const float* __restrict__ w,    // [CO, CI, 3,3,3]
    const float* __restrict__ bias, // [CO]
    half2_t* __restrict__ out,      // [B, CO/2, SP^3] co-pair packed
    int B)
{
    constexpr int SP    = S / 2;
    constexpr int ZD    = 2 * ZT + 2;
    constexpr int YS    = S + 2;
    constexpr int XOFF  = 5;
    constexpr int XR    = S + 8;
    constexpr int PLANE = YS * XR;
    constexpr int NPAIR = BPB * CI * ZD;
    constexpr int LDS_N = NPAIR * PLANE;
    constexpr int NOG   = CO / CPT;
    constexpr int NZB   = ZT / PZT;
    constexpr int NPOS  = NZB * SP * SP;
    constexpr int NSLAB = SP / ZT;
    static_assert(BPB * NOG * NPOS == 256, "thread mapping must cover block");
    static_assert((LDS_N & 3) == 0, "float4 zero");
    static_assert((CPT & 1) == 0, "pack pairs");

    __shared__ __align__(16) float sm[LDS_N];

    const int t     = threadIdx.x;
    const int zslab = blockIdx.x & (NSLAB - 1);
    const int b0    = (blockIdx.x >> clog2(NSLAB)) * BPB;
    const int zp0   = zslab * ZT;
    const int gz0   = 2 * zp0 - 1;

    {   // Phase A: zero LDS
        float4* s4 = (float4*)sm;
        constexpr int N4 = LDS_N / 4;
#pragma unroll
        for (int i = 0; i < (N4 + 255) / 256; ++i) {
            const int k = t + i * 256;
            if (k < N4) s4[k] = make_float4(0.f, 0.f, 0.f, 0.f);
        }
    }
    __syncthreads();

    {   // Phase B: interior rows, float4 loads
        constexpr int CHUNKS = S / 4;
        constexpr int PJOBS  = S * CHUNKS;
        constexpr int PPI    = 256 / PJOBS;
        constexpr int FITER  = NPAIR / PPI;
        static_assert(FITER * PPI == NPAIR, "fill covers planes exactly");
        const int idx  = t & (PJOBS - 1);
        const int poff = t >> clog2(PJOBS);
        const int cc   = idx & (CHUNKS - 1);
        const int yy   = idx >> clog2(CHUNKS);
#pragma unroll
        for (int it = 0; it < FITER; ++it) {
            const int plane = it * PPI + poff;
            const int z     = plane % ZD;
            const int bci   = plane / ZD;
            const int gz    = gz0 + z;
            if ((unsigned)gz < (unsigned)S) {
                const float4 v = *(const float4*)&in[
                    ((long)(b0 * CI + bci) * S + gz) * (S * S) + yy * S + 4 * cc];
                float* sp = &sm[(plane * YS + (yy + 1)) * XR + XOFF + 4 * cc];
                sp[0] = v.x; sp[1] = v.y; sp[2] = v.z; sp[3] = v.w;
            }
        }
    }
    __syncthreads();

    const int pos = t & (NPOS - 1);
    const int og  = __builtin_amdgcn_readfirstlane(
                        (t >> clog2(NPOS)) & (NOG - 1));      // wave-uniform
    const int bl  = __builtin_amdgcn_readfirstlane(
                        t >> clog2(NPOS * NOG));              // wave-uniform
    const int xp  = pos & (SP - 1);
    const int yp  = (pos >> clog2(SP)) & (SP - 1);
    const int zb  = pos >> (2 * clog2(SP));

#pragma unroll 1
    for (int zi = 0; zi < PZT; ++zi) {
        const int zl = zb * PZT + zi;
#pragma unroll 1
        for (int oh = 0; oh < CPT; oh += 2) {
            float acc[2][8];
#pragma unroll
            for (int oo = 0; oo < 2; ++oo)
#pragma unroll
                for (int p = 0; p < 8; ++p) acc[oo][p] = 0.f;

#pragma unroll 1
            for (int ci = 0; ci < CI; ++ci) {
                const float* sp_ = &sm[((bl * CI + ci) * ZD + 2 * zl) * PLANE +
                                       (2 * yp) * XR + 2 * xp + (XOFF - 1)];
#pragma unroll
                for (int dz = 0; dz < 4; ++dz) {
                    float v[4][4];
#pragma unroll
                    for (int dy = 0; dy < 4; ++dy) {
                        const float2 q0 = *(const float2*)&sp_[dz * PLANE + dy * XR];
                        const float2 q1 = *(const float2*)&sp_[dz * PLANE + dy * XR + 2];
                        v[dy][0] = q0.x; v[dy][1] = q0.y;
                        v[dy][2] = q1.x; v[dy][3] = q1.y;
                    }
#pragma unroll
                    for (int kz = 0; kz < 3; ++kz) {
                        const int pz = dz - kz;
                        if (pz >= 0 && pz < 2) {
#pragma unroll
                            for (int oo = 0; oo < 2; ++oo) {
                                const float* wp = w +
                                    (long)((og * CPT + oh + oo) * CI + ci) * 27 +
                                    kz * 9;
#pragma unroll
                                for (int ky = 0; ky < 3; ++ky)
#pragma unroll
                                    for (int kx = 0; kx < 3; ++kx) {
                                        const float wv = wp[ky * 3 + kx];
#pragma unroll
                                        for (int py = 0; py < 2; ++py)
#pragma unroll
                                            for (int px = 0; px < 2; ++px)
                                                acc[oo][pz * 4 + py * 2 + px] +=
                                                    v[py + ky][px + kx] * wv;
                                    }
                            }
                        }
                    }
                }
            }

            const int o = og * CPT + oh;
            float m0 = acc[0][0], m1 = acc[1][0];
#pragma unroll
            for (int p = 1; p < 8; ++p) {
                m0 = fmaxf(m0, acc[0][p]);
                m1 = fmaxf(m1, acc[1][p]);
            }
            half2_t hv;
            hv.x = (_Float16)lrelu(m0 + bias[o]);
            hv.y = (_Float16)lrelu(m1 + bias[o + 1]);
            out[(long)((b0 + bl) * (CO / 2) + (o >> 1)) * (SP * SP * SP) +
                ((zp0 + zl) * SP + yp) * SP + xp] = hv;
        }
    }
}

// ---------------------------------------------------------------------------
// Layer 2 (r4/r5 config, kept): BPB=1, CPT=2, 19KB LDS -> 8 blk/CU,
// merged-zi sweep (acc[2][2][8]=32 regs, each plane read once).
// ---------------------------------------------------------------------------
template<int CIH, int CO, int S, int ZT, int PZT, int CPT, int BPB>
__global__ __launch_bounds__(256, 6) void conv_pool_h2(
    const half2_t* __restrict__ in,  // [B, CIH, S,S,S]
    const uint*   __restrict__ wh,   // [CO, CIH, 27] packed pairs
    const float*  __restrict__ bias, // [CO]
    half2_t* __restrict__ out,       // [B, CO/2, SP^3]
    int B)
{
    constexpr int SP    = S / 2;
    constexpr int ZD    = 2 * ZT + 2;
    constexpr int YS    = S + 2;
    constexpr int XOFF  = 3;
    constexpr int XR    = S + 6;
    constexpr int PLANE = YS * XR;
    constexpr int NPAIR = BPB * CIH * ZD;
    constexpr int LDS_N = NPAIR * PLANE;
    constexpr int NOG   = CO / CPT;
    constexpr int NZB   = ZT / PZT;
    constexpr int NPOS  = NZB * SP * SP;
    constexpr int NSLAB = SP / ZT;
    static_assert(BPB * NOG * NPOS == 256, "thread mapping must cover block");
    static_assert((LDS_N & 3) == 0, "uint4 zero");
    static_assert((CPT & 1) == 0, "pack pairs");

    __shared__ __align__(16) uint sm[LDS_N];
    const uint* inu = (const uint*)in;

    const int t     = threadIdx.x;
    const int zslab = blockIdx.x & (NSLAB - 1);
    const int b0    = (blockIdx.x >> clog2(NSLAB)) * BPB;
    const int zp0   = zslab * ZT;
    const int gz0   = 2 * zp0 - 1;

    {   // Phase A: zero LDS
        uint4* s4 = (uint4*)sm;
        constexpr int N4 = LDS_N / 4;
#pragma unroll
        for (int i = 0; i < (N4 + 255) / 256; ++i) {
            const int k = t + i * 256;
            if (k < N4) s4[k] = make_uint4(0, 0, 0, 0);
        }
    }
    __syncthreads();

    {   // Phase B: interior rows, uint2 global loads
        constexpr int CH    = S / 2;
        constexpr int PJOBS = S * CH;
        constexpr int ITERS = NPAIR * PJOBS / 256;
        static_assert(ITERS * 256 == NPAIR * PJOBS, "exact fill");
#pragma unroll
        for (int it = 0; it < ITERS; ++it) {
            const int i     = t + it * 256;
            const int idx   = i & (PJOBS - 1);
            const int plane = i >> clog2(PJOBS);
            const int cc    = idx & (CH - 1);
            const int yy    = idx >> clog2(CH);
            const int z     = plane % ZD;
            const int bci   = plane / ZD;
            const int gz    = gz0 + z;
            if ((unsigned)gz < (unsigned)S) {
                const uint2 v = *(const uint2*)&inu[
                    ((long)(b0 * CIH + bci) * S + gz) * (S * S) + yy * S + 2 * cc];
                uint* sp = &sm[(plane * YS + yy + 1) * XR + XOFF + 2 * cc];
                sp[0] = v.x; sp[1] = v.y;
            }
        }
    }
    __syncthreads();

    const int pos = t & (NPOS - 1);
    const int og  = __builtin_amdgcn_readfirstlane(
                        (t >> clog2(NPOS)) & (NOG - 1));       // wave-uniform
    const int bl  = __builtin_amdgcn_readfirstlane(
                        t >> clog2(NPOS * NOG));               // wave-uniform
    const int xp  = pos & (SP - 1);
    const int yp  = (pos >> clog2(SP)) & (SP - 1);
    const int zb  = pos >> (2 * clog2(SP));

    float acc[PZT][CPT][8];
#pragma unroll
    for (int zi = 0; zi < PZT; ++zi)
#pragma unroll
        for (int oo = 0; oo < CPT; ++oo)
#pragma unroll
            for (int p = 0; p < 8; ++p) acc[zi][oo][p] = 0.f;

#pragma unroll 1
    for (int cp = 0; cp < CIH; ++cp) {
        const uint* sp_ = &sm[((bl * CIH + cp) * ZD + 2 * zb * PZT) * PLANE +
                              (2 * yp) * XR + 2 * xp + (XOFF - 1)]; // even
#pragma unroll
        for (int dz = 0; dz < 2 * PZT + 2; ++dz) {
            half2_t v[4][4];
#pragma unroll
            for (int dy = 0; dy < 4; ++dy) {
                const uint2 q0 = *(const uint2*)&sp_[dz * PLANE + dy * XR];
                const uint2 q1 = *(const uint2*)&sp_[dz * PLANE + dy * XR + 2];
                v[dy][0] = as_h2(q0.x); v[dy][1] = as_h2(q0.y);
                v[dy][2] = as_h2(q1.x); v[dy][3] = as_h2(q1.y);
            }
#pragma unroll
            for (int zi = 0; zi < PZT; ++zi) {
                const int dzl = dz - 2 * zi;
                if (dzl >= 0 && dzl < 4) {
#pragma unroll
                    for (int kz = 0; kz < 3; ++kz) {
                        const int pz = dzl - kz;
                        if (pz >= 0 && pz < 2) {
#pragma unroll
                            for (int oo = 0; oo < CPT; ++oo) {
                                const uint* wp = wh +
                                    (long)((og * CPT + oo) * CIH + cp) * 27 + kz * 9;
#pragma unroll
                                for (int ky = 0; ky < 3; ++ky)
#pragma unroll
                                    for (int kx = 0; kx < 3; ++kx) {
                                        const half2_t wv = as_h2(wp[ky * 3 + kx]);
#pragma unroll
                                        for (int py = 0; py < 2; ++py)
#pragma unroll
                                            for (int px = 0; px < 2; ++px)
                                                acc[zi][oo][pz * 4 + py * 2 + px] =
                                                    fdot2(v[py + ky][px + kx], wv,
                                                          acc[zi][oo][pz * 4 + py * 2 + px]);
                                    }
                            }
                        }
                    }
                }
            }
        }
    }

#pragma unroll
    for (int zi = 0; zi < PZT; ++zi) {
        const int zl = zb * PZT + zi;
#pragma unroll
        for (int oo = 0; oo < CPT; oo += 2) {
            const int o = og * CPT + oo;
            float m0 = acc[zi][oo][0], m1 = acc[zi][oo + 1][0];
#pragma unroll
            for (int p = 1; p < 8; ++p) {
                m0 = fmaxf(m0, acc[zi][oo][p]);
                m1 = fmaxf(m1, acc[zi][oo + 1][p]);
            }
            half2_t hv;
            hv.x = (_Float16)lrelu(m0 + bias[o]);
            hv.y = (_Float16)lrelu(m1 + bias[o + 1]);
            out[(long)((b0 + bl) * (CO / 2) + (o >> 1)) * (SP * SP * SP) +
                ((zp0 + zl) * SP + yp) * SP + xp] = hv;
        }
    }
}

// ---------------------------------------------------------------------------
// Fused tail (unchanged from r3..r6 passing builds).
// ---------------------------------------------------------------------------
__global__ __launch_bounds__(256, 4) void tail_fused2(
    const uint*  __restrict__ in,   // buf2h [B][4][8^3] half2 words
    const uint*  __restrict__ wh3,  // [16][4][27]
    const uint*  __restrict__ wh4,  // [32][8][27]
    const uint*  __restrict__ wh5,  // [64][16][27]
    const float* __restrict__ cb3, const float* __restrict__ cb4,
    const float* __restrict__ cb5,
    const float* __restrict__ W1, const float* __restrict__ fb1,
    const float* __restrict__ W2, const float* __restrict__ fb2,
    const float* __restrict__ W3, const float* __restrict__ fb3,
    float* __restrict__ out)        // [B,6,4]
{
    constexpr int S3IN  = 0;
    constexpr int S3OUT = 4800;
    constexpr int S4OUT = 6528;
    constexpr int FEAT  = 7552;
    constexpr int H1O   = 7616;
    constexpr int H2O   = 7808;
    constexpr int H3O   = 7904;
    constexpr int LDS_N = 7936;

    __shared__ __align__(16) uint sm[LDS_N];
    float* smf = (float*)sm;
    _Float16* s3h = (_Float16*)(sm + S3OUT);
    _Float16* s4h = (_Float16*)(sm + S4OUT);

    const int t = threadIdx.x;
    const int b = blockIdx.x;

    {
        uint4* s4 = (uint4*)sm;
#pragma unroll
        for (int i = 0; i < 8; ++i) {
            const int k = t + i * 256;
            if (k < LDS_N / 4) s4[k] = make_uint4(0, 0, 0, 0);
        }
    }
    __syncthreads();

#pragma unroll
    for (int it = 0; it < 4; ++it) {
        const int i  = t + it * 256;
        const int xc = i & 3;
        const int yy = (i >> 2) & 7;
        const int zz = (i >> 5) & 7;
        const int cp = i >> 8;
        const uint2 v = *(const uint2*)&in[
            ((long)b * 4 + cp) * 512 + (zz * 8 + yy) * 8 + 2 * xc];
        uint* sp = &sm[S3IN + cp * 1200 + (zz + 1) * 120 + (yy + 1) * 12 +
                       3 + 2 * xc];
        sp[0] = v.x; sp[1] = v.y;
    }
    __syncthreads();

    // ---- L3: pos64 x cog4 (wave-uniform), 4 co per thread ----
    {
        const int pos = t & 63;
        const int cog = __builtin_amdgcn_readfirstlane(t >> 6);
        const int xp = pos & 3;
        const int yp = (pos >> 2) & 3;
        const int zp = pos >> 4;

        float acc[4][8];
#pragma unroll
        for (int oo = 0; oo < 4; ++oo)
#pragma unroll
            for (int p = 0; p < 8; ++p) acc[oo][p] = 0.f;

#pragma unroll 1
        for (int cp = 0; cp < 4; ++cp) {
            const uint* base = &sm[S3IN + cp * 1200 + 2 * zp * 120 +
                                   2 * yp * 12 + 2 * xp + 2];
#pragma unroll
            for (int dz = 0; dz < 4; ++dz) {
                half2_t v[4][4];
#pragma unroll
                for (int dy = 0; dy < 4; ++dy) {
                    const uint2 q0 = *(const uint2*)&base[dz * 120 + dy * 12];
                    const uint2 q1 = *(const uint2*)&base[dz * 120 + dy * 12 + 2];
                    v[dy][0] = as_h2(q0.x); v[dy][1] = as_h2(q0.y);
                    v[dy][2] = as_h2(q1.x); v[dy][3] = as_h2(q1.y);
                }
#pragma unroll
                for (int kz = 0; kz < 3; ++kz) {
                    const int pz = dz - kz;
                    if (pz >= 0 && pz < 2) {
#pragma unroll
                        for (int oo = 0; oo < 4; ++oo) {
                            const uint* wp = &wh3[((cog * 4 + oo) * 4 + cp) * 27 +
                                                  kz * 9];
#pragma unroll
                            for (int ky = 0; ky < 3; ++ky)
#pragma unroll
                                for (int kx = 0; kx < 3; ++kx) {
                                    const half2_t wv = as_h2(wp[ky * 3 + kx]);
#pragma unroll
                                    for (int py = 0; py < 2; ++py)
#pragma unroll
                                        for (int px = 0; px < 2; ++px)
                                            acc[oo][pz * 4 + py * 2 + px] =
                                                fdot2(v[py + ky][px + kx], wv,
                                                      acc[oo][pz * 4 + py * 2 + px]);
                                }
                        }
                    }
                }
            }
        }
        const int hbase = (((zp + 1) * 6 + (yp + 1)) * 6 + (xp + 1)) << 4;
#pragma unroll
        for (int oo = 0; oo < 4; ++oo) {
            const int co = cog * 4 + oo;
            float m = acc[oo][0];
#pragma unroll
            for (int p = 1; p < 8; ++p) m = fmaxf(m, acc[oo][p]);
            s3h[hbase + co] = (_Float16)lrelu(m + cb3[co]);
        }
    }
    __syncthreads();

    // ---- L4: pos8 x co32 ----
    {
        const int co = t >> 3;
        const int pos = t & 7;
        const int xp = pos & 1;
        const int yp = (pos >> 1) & 1;
        const int zp = pos >> 2;
        const uint* vbase = &sm[S3OUT + (((2 * zp * 6 + 2 * yp) * 6 + 2 * xp) << 3)];
        float acc[8];
#pragma unroll
        for (int p = 0; p < 8; ++p) acc[p] = 0.f;
#pragma unroll 1
        for (int c = 0; c < 8; ++c) {
            const uint* wp = &wh4[(co * 8 + c) * 27];
#pragma unroll
            for (int dz = 0; dz < 4; ++dz) {
                half2_t v[4][4];
#pragma unroll
                for (int dy = 0; dy < 4; ++dy)
#pragma unroll
                    for (int dx = 0; dx < 4; ++dx)
                        v[dy][dx] = as_h2(vbase[(((dz * 6 + dy) * 6 + dx) << 3) + c]);
#pragma unroll
                for (int kz = 0; kz < 3; ++kz) {
                    const int pz = dz - kz;
                    if (pz >= 0 && pz < 2) {
#pragma unroll
                        for (int ky = 0; ky < 3; ++ky)
#pragma unroll
                            for (int kx = 0; kx < 3; ++kx) {
                                const half2_t wv = as_h2(wp[kz * 9 + ky * 3 + kx]);
#pragma unroll
                                for (int py = 0; py < 2; ++py)
#pragma unroll
                                    for (int px = 0; px < 2; ++px)
                                        acc[pz * 4 + py * 2 + px] =
                                            fdot2(v[py + ky][px + kx], wv,
                                                  acc[pz * 4 + py * 2 + px]);
                            }
                    }
                }
            }
        }
        float m = acc[0];
#pragma unroll
        for (int p = 1; p < 8; ++p) m = fmaxf(m, acc[p]);
        s4h[((((zp + 1) * 4 + (yp + 1)) * 4 + (xp + 1)) << 5) + co] =
            (_Float16)lrelu(m + cb4[co]);
    }
    __syncthreads();

    // ---- L5: co64 x cq4 partials ----
    {
        const int co = t & 63;
        const int cq = __builtin_amdgcn_readfirstlane(t >> 6);
        float acc[8];
#pragma unroll
        for (int p = 0; p < 8; ++p) acc[p] = 0.f;
#pragma unroll 1
        for (int ci = 0; ci < 4; ++ci) {
            const int c = cq * 4 + ci;
            const uint* wp = &wh5[(co * 16 + c) * 27];
#pragma unroll
            for (int dz = 0; dz < 4; ++dz) {
                half2_t v[4][4];
#pragma unroll
                for (int dy = 0; dy < 4; ++dy)
#pragma unroll
                    for (int dx = 0; dx < 4; ++dx)
                        v[dy][dx] = as_h2(sm[S4OUT +
                            (((dz * 4 + dy) * 4 + dx) << 4) + c]);
#pragma unroll
                for (int kz = 0; kz < 3; ++kz) {
                    const int pz = dz - kz;
                    if (pz >= 0 && pz < 2) {
#pragma unroll
                        for (int ky = 0; ky < 3; ++ky)
#pragma unroll
                            for (int kx = 0; kx < 3; ++kx) {
                                const half2_t wv = as_h2(wp[kz * 9 + ky * 3 + kx]);
#pragma unroll
                                for (int py = 0; py < 2; ++py)
#pragma unroll
                                    for (int px = 0; px < 2; ++px)
                                        acc[pz * 4 + py * 2 + px] =
                                            fdot2(v[py + ky][px + kx], wv,
                                                  acc[pz * 4 + py * 2 + px]);
                            }
                    }
                }
            }
        }
#pragma unroll
        for (int p = 0; p < 8; ++p)
            smf[(cq * 64 + co) * 9 + p] = acc[p];
    }
    __syncthreads();

    if (t < 64) {
        float acc[8];
#pragma unroll
        for (int p = 0; p < 8; ++p)
            acc[p] = smf[t * 9 + p] + smf[(64 + t) * 9 + p] +
                     smf[(128 + t) * 9 + p] + smf[(192 + t) * 9 + p];
        float m = acc[0];
#pragma unroll
        for (int p = 1; p < 8; ++p) m = fmaxf(m, acc[p]);
        smf[FEAT + t] = lrelu(m + cb5[t]);
    }
    __syncthreads();

    if (t < 192) {
        const int j = t & 31;
        const int h = t >> 5;
        float s = fb1[h * 32 + j];
#pragma unroll
        for (int k = 0; k < 64; ++k)
            s += smf[FEAT + k] * W1[(h * 64 + k) * 32 + j];
        smf[H1O + h * 32 + j] = lrelu(s);
    }
    __syncthreads();

    if (t < 96) {
        const int j = t & 15;
        const int h = t >> 4;
        float s = fb2[h * 16 + j];
#pragma unroll
        for (int k = 0; k < 32; ++k)
            s += smf[H1O + h * 32 + k] * W2[(h * 32 + k) * 16 + j];
        smf[H2O + h * 16 + j] = lrelu(s);
    }
    __syncthreads();

    if (t < 24) {
        const int j = t & 3;
        const int h = t >> 2;
        float s = fb3[h * 4 + j];
#pragma unroll
        for (int k = 0; k < 16; ++k)
            s += smf[H2O + h * 16 + k] * W3[(h * 16 + k) * 4 + j];
        smf[H3O + h * 4 + j] = lrelu(s);
    }
    __syncthreads();

    if (t < 24) {
        const int q = t & 3;
        const int h = t >> 2;
        const float x0 = smf[H3O + h * 4 + 0];
        const float x1 = smf[H3O + h * 4 + 1];
        const float x2 = smf[H3O + h * 4 + 2];
        const float x3 = smf[H3O + h * 4 + 3];
        const float inv = 1.f / sqrtf(x0 * x0 + x1 * x1 + x2 * x2 + x3 * x3);
        out[(b * 6 + h) * 4 + q] = smf[H3O + h * 4 + q] * inv;
    }
}

// ---------------------------------------------------------------------------
// Weight pre-pack: fp32 [CO][CI][27] -> half2 [CO][CI/2][27] (pairs over ci).
// ---------------------------------------------------------------------------
__device__ __forceinline__ void pack_one(int i, const float* w, uint* h,
                                         int CO, int CI)
{
    const int CIH = CI / 2;
    const int n = CO * CIH * 27;
    if (i < n) {
        const int tap = i % 27;
        const int r   = i / 27;
        const int cp  = r % CIH;
        const int co  = r / CIH;
        const float* s = w + ((co * CI + 2 * cp) * 27 + tap);
        union { uint u; half2_t v; } c;
        c.v.x = (_Float16)s[0];
        c.v.y = (_Float16)s[27];
        h[i] = c.u;
    }
}

__global__ __launch_bounds__(256) void pack_weights(
    const float* w2, const float* w3, const float* w4, const float* w5,
    uint* h2, uint* h3, uint* h4, uint* h5)
{
    const int i = blockIdx.x * 256 + threadIdx.x;
    pack_one(i, w2, h2, 8, 4);
    pack_one(i, w3, h3, 16, 8);
    pack_one(i, w4, h4, 32, 16);
    pack_one(i, w5, h5, 64, 32);
}

extern "C" void kernel_launch(void* const* d_in, const int* in_sizes, int n_in,
                              void* d_out, int out_size, void* d_ws, size_t ws_size,
                              hipStream_t stream)
{
    const float* voxel = (const float*)d_in[0];
    const float* cw1 = (const float*)d_in[1];  const float* cb1 = (const float*)d_in[2];
    const float* cw2 = (const float*)d_in[3];  const float* cb2 = (const float*)d_in[4];
    const float* cw3 = (const float*)d_in[5];  const float* cb3 = (const float*)d_in[6];
    const float* cw4 = (const float*)d_in[7];  const float* cb4 = (const float*)d_in[8];
    const float* cw5 = (const float*)d_in[9];  const float* cb5 = (const float*)d_in[10];
    const float* W1  = (const float*)d_in[11]; const float* b1  = (const float*)d_in[12];
    const float* W2  = (const float*)d_in[13]; const float* b2  = (const float*)d_in[14];
    const float* W3  = (const float*)d_in[15]; const float* b3  = (const float*)d_in[16];
    float* out = (float*)d_out;

    const int B = 1024;
    uint* buf1h = (uint*)d_ws;                 // [1024][2][16^3]  8388608 w
    uint* buf2h = buf1h + 8388608;             // [1024][4][8^3]   2097152 w
    uint* wh2   = buf2h + 2097152;             // 432
    uint* wh3   = wh2 + 432;                   // 1728
    uint* wh4   = wh3 + 1728;                  // 6912
    uint* wh5   = wh4 + 6912;                  // 27648

    pack_weights<<<108, 256, 0, stream>>>(cw2, cw3, cw4, cw5, wh2, wh3, wh4, wh5);

    // L1: 1->4, 32^3->16^3 (fp32, plane-wise, co-pair split passes)
    conv_pool_f32h<1, 4, 32, 2, 2, 4, 1><<<1024 * 8, 256, 0, stream>>>(
        voxel, cw1, cb1, (half2_t*)buf1h, B);
    // L2: CIH=2, 16^3->8^3 (dot2, BPB=1 CPT=2: 19KB LDS, 8 blk/CU, merged-zi)
    conv_pool_h2<2, 8, 16, 2, 2, 2, 1><<<1024 * 4, 256, 0, stream>>>(
        (const half2_t*)buf1h, wh2, cb2, (half2_t*)buf2h, B);
    // L3+L4+L5+FC fused: 1 batch/block (unchanged)
    tail_fused2<<<1024, 256, 0, stream>>>(
        buf2h, wh3, wh4, wh5, cb3, cb4, cb5,
        W1, b1, W2, b2, W3, b3, out);
}

// Round 8
// 378.129 us; speedup vs baseline: 3.4608x; 1.1228x over previous
//
#include <hip/hip_runtime.h>
#include <math.h>

#define NEG_SLOPE 0.2f

typedef _Float16 half2_t __attribute__((ext_vector_type(2)));

__device__ __forceinline__ float lrelu(float x) {
    return fmaxf(x, NEG_SLOPE * x);
}

__device__ __forceinline__ float fdot2(half2_t a, half2_t b, float c) {
#if __has_builtin(__builtin_amdgcn_fdot2)
    return __builtin_amdgcn_fdot2(a, b, c, false);
#else
    return c + (float)a.x * (float)b.x + (float)a.y * (float)b.y;
#endif
}

__device__ __forceinline__ half2_t as_h2(uint u) {
    union { uint u; half2_t h; } c; c.u = u; return c.h;
}

// float2 with guaranteed arithmetic (pairs -> v_pk_fma_f32 on gfx90a+)
struct f2 { float x, y; };
__device__ __forceinline__ f2 mk2(float a, float b) { f2 r; r.x = a; r.y = b; return r; }

typedef float v2f __attribute__((ext_vector_type(2)));
__device__ __forceinline__ v2f as_v2(f2 a) { v2f r; r.x = a.x; r.y = a.y; return r; }

constexpr int clog2(int n) { return (n <= 1) ? 0 : 1 + clog2(n / 2); }

// ---------------------------------------------------------------------------
// Layer 1 (fp32, CI=1). r8: PACKED FP32 FMA (v_pk_fma_f32, 2 MAC/inst).
// r7 established L1 is VALU-instruction-count bound (~2.6 inst/FMA after all
// allocation games). Pair the px in {0,1} outputs into one float2 lane pair:
// q0=(x0,x1) / q1=(x2,x3) are natural pairs from the b64 LDS reads; only the
// kx=1 tap needs p12=(x1,x2) (2 movs/dy, amortized). acc becomes
// v2f acc[2][4] (lane=px). Tap order per acc element unchanged (ky->kx asc,
// fma chain) -> bitwise identical output. FMA inst 1728 -> 864(+64 movs).
// ---------------------------------------------------------------------------
template<int CI, int CO, int S, int ZT, int PZT, int CPT, int BPB>
__global__ __launch_bounds__(256, 4) void conv_pool_f32h(
    const float* __restrict__ in,   // [B, CI, S,S,S]
    const float* __restrict__ w,    // [CO, CI, 3,3,3]
    const float* __restrict__ bias, // [CO]
    half2_t* __restrict__ out,      // [B, CO/2, SP^3] co-pair packed
    int B)
{
    constexpr int SP    = S / 2;
    constexpr int ZD    = 2 * ZT + 2;
    constexpr int YS    = S + 2;
    constexpr int XOFF  = 5;
    constexpr int XR    = S + 8;
    constexpr int PLANE = YS * XR;
    constexpr int NPAIR = BPB * CI * ZD;
    constexpr int LDS_N = NPAIR * PLANE;
    constexpr int NOG   = CO / CPT;
    constexpr int NZB   = ZT / PZT;
    constexpr int NPOS  = NZB * SP * SP;
    constexpr int NSLAB = SP / ZT;
    static_assert(BPB * NOG * NPOS == 256, "thread mapping must cover block");
    static_assert((LDS_N & 3) == 0, "float4 zero");
    static_assert((CPT & 1) == 0, "pack pairs");

    __shared__ __align__(16) float sm[LDS_N];

    const int t     = threadIdx.x;
    const int zslab = blockIdx.x & (NSLAB - 1);
    const int b0    = (blockIdx.x >> clog2(NSLAB)) * BPB;
    const int zp0   = zslab * ZT;
    const int gz0   = 2 * zp0 - 1;

    {   // Phase A: zero LDS
        float4* s4 = (float4*)sm;
        constexpr int N4 = LDS_N / 4;
#pragma unroll
        for (int i = 0; i < (N4 + 255) / 256; ++i) {
            const int k = t + i * 256;
            if (k < N4) s4[k] = make_float4(0.f, 0.f, 0.f, 0.f);
        }
    }
    __syncthreads();

    {   // Phase B: interior rows, float4 loads
        constexpr int CHUNKS = S / 4;
        constexpr int PJOBS  = S * CHUNKS;
        constexpr int PPI    = 256 / PJOBS;
        constexpr int FITER  = NPAIR / PPI;
        static_assert(FITER * PPI == NPAIR, "fill covers planes exactly");
        const int idx  = t & (PJOBS - 1);
        const int poff = t >> clog2(PJOBS);
        const int cc   = idx & (CHUNKS - 1);
        const int yy   = idx >> clog2(CHUNKS);
#pragma unroll
        for (int it = 0; it < FITER; ++it) {
            const int plane = it * PPI + poff;
            const int z     = plane % ZD;
            const int bci   = plane / ZD;
            const int gz    = gz0 + z;
            if ((unsigned)gz < (unsigned)S) {
                const float4 v = *(const float4*)&in[
                    ((long)(b0 * CI + bci) * S + gz) * (S * S) + yy * S + 4 * cc];
                float* sp = &sm[(plane * YS + (yy + 1)) * XR + XOFF + 4 * cc];
                sp[0] = v.x; sp[1] = v.y; sp[2] = v.z; sp[3] = v.w;
            }
        }
    }
    __syncthreads();

    const int pos = t & (NPOS - 1);
    const int og  = __builtin_amdgcn_readfirstlane(
                        (t >> clog2(NPOS)) & (NOG - 1));      // wave-uniform
    const int bl  = __builtin_amdgcn_readfirstlane(
                        t >> clog2(NPOS * NOG));              // wave-uniform
    const int xp  = pos & (SP - 1);
    const int yp  = (pos >> clog2(SP)) & (SP - 1);
    const int zb  = pos >> (2 * clog2(SP));

#pragma unroll 1
    for (int zi = 0; zi < PZT; ++zi) {
        const int zl = zb * PZT + zi;
#pragma unroll 1
        for (int oh = 0; oh < CPT; oh += 2) {
            // acc[oo][pz*2+py], vector lane = px in {0,1}
            v2f acc[2][4];
#pragma unroll
            for (int oo = 0; oo < 2; ++oo)
#pragma unroll
                for (int j = 0; j < 4; ++j) { acc[oo][j].x = 0.f; acc[oo][j].y = 0.f; }

#pragma unroll 1
            for (int ci = 0; ci < CI; ++ci) {
                const float* sp_ = &sm[((bl * CI + ci) * ZD + 2 * zl) * PLANE +
                                       (2 * yp) * XR + 2 * xp + (XOFF - 1)];
#pragma unroll
                for (int dz = 0; dz < 4; ++dz) {
                    // per-row pair registers: (x0,x1) (x1,x2) (x2,x3)
                    v2f p01[4], p12[4], p23[4];
#pragma unroll
                    for (int dy = 0; dy < 4; ++dy) {
                        const float2 q0 = *(const float2*)&sp_[dz * PLANE + dy * XR];
                        const float2 q1 = *(const float2*)&sp_[dz * PLANE + dy * XR + 2];
                        p01[dy].x = q0.x; p01[dy].y = q0.y;
                        p12[dy].x = q0.y; p12[dy].y = q1.x;
                        p23[dy].x = q1.x; p23[dy].y = q1.y;
                    }
#pragma unroll
                    for (int kz = 0; kz < 3; ++kz) {
                        const int pz = dz - kz;
                        if (pz >= 0 && pz < 2) {
#pragma unroll
                            for (int oo = 0; oo < 2; ++oo) {
                                const float* wp = w +
                                    (long)((og * CPT + oh + oo) * CI + ci) * 27 +
                                    kz * 9;
#pragma unroll
                                for (int ky = 0; ky < 3; ++ky) {
                                    const float w0 = wp[ky * 3 + 0];
                                    const float w1 = wp[ky * 3 + 1];
                                    const float w2 = wp[ky * 3 + 2];
#pragma unroll
                                    for (int py = 0; py < 2; ++py) {
                                        const int r = py + ky;
                                        v2f a = acc[oo][pz * 2 + py];
                                        a += p01[r] * w0;   // kx=0 (both px)
                                        a += p12[r] * w1;   // kx=1
                                        a += p23[r] * w2;   // kx=2
                                        acc[oo][pz * 2 + py] = a;
                                    }
                                }
                            }
                        }
                    }
                }
            }

            const int o = og * CPT + oh;
            // maxpool: same comparison order as the scalar acc[0..7] walk
            float m0 = acc[0][0].x, m1 = acc[1][0].x;
            m0 = fmaxf(m0, acc[0][0].y); m1 = fmaxf(m1, acc[1][0].y);
#pragma unroll
            for (int j = 1; j < 4; ++j) {
                m0 = fmaxf(m0, acc[0][j].x); m0 = fmaxf(m0, acc[0][j].y);
                m1 = fmaxf(m1, acc[1][j].x); m1 = fmaxf(m1, acc[1][j].y);
            }
            half2_t hv;
            hv.x = (_Float16)lrelu(m0 + bias[o]);
            hv.y = (_Float16)lrelu(m1 + bias[o + 1]);
            out[(long)((b0 + bl) * (CO / 2) + (o >> 1)) * (SP * SP * SP) +
                ((zp0 + zl) * SP + yp) * SP + xp] = hv;
        }
    }
}

// ---------------------------------------------------------------------------
// Layer 2 (r4..r7 config, kept): BPB=1, CPT=2, 19KB LDS -> 8 blk/CU,
// merged-zi sweep (acc[2][2][8]=32 regs, each plane read once).
// ---------------------------------------------------------------------------
template<int CIH, int CO, int S, int ZT, int PZT, int CPT, int BPB>
__global__ __launch_bounds__(256, 6) void conv_pool_h2(
    const half2_t* __restrict__ in,  // [B, CIH, S,S,S]
    const uint*   __restrict__ wh,   // [CO, CIH, 27] packed pairs
    const float*  __restrict__ bias, // [CO]
    half2_t* __restrict__ out,       // [B, CO/2, SP^3]
    int B)
{
    constexpr int SP    = S / 2;
    constexpr int ZD    = 2 * ZT + 2;
    constexpr int YS    = S + 2;
    constexpr int XOFF  = 3;
    constexpr int XR    = S + 6;
    constexpr int PLANE = YS * XR;
    constexpr int NPAIR = BPB * CIH * ZD;
    constexpr int LDS_N = NPAIR * PLANE;
    constexpr int NOG   = CO / CPT;
    constexpr int NZB   = ZT / PZT;
    constexpr int NPOS  = NZB * SP * SP;
    constexpr int NSLAB = SP / ZT;
    static_assert(BPB * NOG * NPOS == 256, "thread mapping must cover block");
    static_assert((LDS_N & 3) == 0, "uint4 zero");
    static_assert((CPT & 1) == 0, "pack pairs");

    __shared__ __align__(16) uint sm[LDS_N];
    const uint* inu = (const uint*)in;

    const int t     = threadIdx.x;
    const int zslab = blockIdx.x & (NSLAB - 1);
    const int b0    = (blockIdx.x >> clog2(NSLAB)) * BPB;
    const int zp0   = zslab * ZT;
    const int gz0   = 2 * zp0 - 1;

    {   // Phase A: zero LDS
        uint4* s4 = (uint4*)sm;
        constexpr int N4 = LDS_N / 4;
#pragma unroll
        for (int i = 0; i < (N4 + 255) / 256; ++i) {
            const int k = t + i * 256;
            if (k < N4) s4[k] = make_uint4(0, 0, 0, 0);
        }
    }
    __syncthreads();

    {   // Phase B: interior rows, uint2 global loads
        constexpr int CH    = S / 2;
        constexpr int PJOBS = S * CH;
        constexpr int ITERS = NPAIR * PJOBS / 256;
        static_assert(ITERS * 256 == NPAIR * PJOBS, "exact fill");
#pragma unroll
        for (int it = 0; it < ITERS; ++it) {
            const int i     = t + it * 256;
            const int idx   = i & (PJOBS - 1);
            const int plane = i >> clog2(PJOBS);
            const int cc    = idx & (CH - 1);
            const int yy    = idx >> clog2(CH);
            const int z     = plane % ZD;
            const int bci   = plane / ZD;
            const int gz    = gz0 + z;
            if ((unsigned)gz < (unsigned)S) {
                const uint2 v = *(const uint2*)&inu[
                    ((long)(b0 * CIH + bci) * S + gz) * (S * S) + yy * S + 2 * cc];
                uint* sp = &sm[(plane * YS + yy + 1) * XR + XOFF + 2 * cc];
                sp[0] = v.x; sp[1] = v.y;
            }
        }
    }
    __syncthreads();

    const int pos = t & (NPOS - 1);
    const int og  = __builtin_amdgcn_readfirstlane(
                        (t >> clog2(NPOS)) & (NOG - 1));       // wave-uniform
    const int bl  = __builtin_amdgcn_readfirstlane(
                        t >> clog2(NPOS * NOG));               // wave-uniform
    const int xp  = pos & (SP - 1);
    const int yp  = (pos >> clog2(SP)) & (SP - 1);
    const int zb  = pos >> (2 * clog2(SP));

    float acc[PZT][CPT][8];
#pragma unroll
    for (int zi = 0; zi < PZT; ++zi)
#pragma unroll
        for (int oo = 0; oo < CPT; ++oo)
#pragma unroll
            for (int p = 0; p < 8; ++p) acc[zi][oo][p] = 0.f;

#pragma unroll 1
    for (int cp = 0; cp < CIH; ++cp) {
        const uint* sp_ = &sm[((bl * CIH + cp) * ZD + 2 * zb * PZT) * PLANE +
                              (2 * yp) * XR + 2 * xp + (XOFF - 1)]; // even
#pragma unroll
        for (int dz = 0; dz < 2 * PZT + 2; ++dz) {
            half2_t v[4][4];
#pragma unroll
            for (int dy = 0; dy < 4; ++dy) {
                const uint2 q0 = *(const uint2*)&sp_[dz * PLANE + dy * XR];
                const uint2 q1 = *(const uint2*)&sp_[dz * PLANE + dy * XR + 2];
                v[dy][0] = as_h2(q0.x); v[dy][1] = as_h2(q0.y);
                v[dy][2] = as_h2(q1.x); v[dy][3] = as_h2(q1.y);
            }
#pragma unroll
            for (int zi = 0; zi < PZT; ++zi) {
                const int dzl = dz - 2 * zi;
                if (dzl >= 0 && dzl < 4) {
#pragma unroll
                    for (int kz = 0; kz < 3; ++kz) {
                        const int pz = dzl - kz;
                        if (pz >= 0 && pz < 2) {
#pragma unroll
                            for (int oo = 0; oo < CPT; ++oo) {
                                const uint* wp = wh +
                                    (long)((og * CPT + oo) * CIH + cp) * 27 + kz * 9;
#pragma unroll
                                for (int ky = 0; ky < 3; ++ky)
#pragma unroll
                                    for (int kx = 0; kx < 3; ++kx) {
                                        const half2_t wv = as_h2(wp[ky * 3 + kx]);
#pragma unroll
                                        for (int py = 0; py < 2; ++py)
#pragma unroll
                                            for (int px = 0; px < 2; ++px)
                                                acc[zi][oo][pz * 4 + py * 2 + px] =
                                                    fdot2(v[py + ky][px + kx], wv,
                                                          acc[zi][oo][pz * 4 + py * 2 + px]);
                                    }
                            }
                        }
                    }
                }
            }
        }
    }

#pragma unroll
    for (int zi = 0; zi < PZT; ++zi) {
        const int zl = zb * PZT + zi;
#pragma unroll
        for (int oo = 0; oo < CPT; oo += 2) {
            const int o = og * CPT + oo;
            float m0 = acc[zi][oo][0], m1 = acc[zi][oo + 1][0];
#pragma unroll
            for (int p = 1; p < 8; ++p) {
                m0 = fmaxf(m0, acc[zi][oo][p]);
                m1 = fmaxf(m1, acc[zi][oo + 1][p]);
            }
            half2_t hv;
            hv.x = (_Float16)lrelu(m0 + bias[o]);
            hv.y = (_Float16)lrelu(m1 + bias[o + 1]);
            out[(long)((b0 + bl) * (CO / 2) + (o >> 1)) * (SP * SP * SP) +
                ((zp0 + zl) * SP + yp) * SP + xp] = hv;
        }
    }
}

// ---------------------------------------------------------------------------
// Fused tail (unchanged from r3..r7 passing builds).
// ---------------------------------------------------------------------------
__global__ __launch_bounds__(256, 4) void tail_fused2(
    const uint*  __restrict__ in,   // buf2h [B][4][8^3] half2 words
    const uint*  __restrict__ wh3,  // [16][4][27]
    const uint*  __restrict__ wh4,  // [32][8][27]
    const uint*  __restrict__ wh5,  // [64][16][27]
    const float* __restrict__ cb3, const float* __restrict__ cb4,
    const float* __restrict__ cb5,
    const float* __restrict__ W1, const float* __restrict__ fb1,
    const float* __restrict__ W2, const float* __restrict__ fb2,
    const float* __restrict__ W3, const float* __restrict__ fb3,
    float* __restrict__ out)        // [B,6,4]
{
    constexpr int S3IN  = 0;
    constexpr int S3OUT = 4800;
    constexpr int S4OUT = 6528;
    constexpr int FEAT  = 7552;
    constexpr int H1O   = 7616;
    constexpr int H2O   = 7808;
    constexpr int H3O   = 7904;
    constexpr int LDS_N = 7936;

    __shared__ __align__(16) uint sm[LDS_N];
    float* smf = (float*)sm;
    _Float16* s3h = (_Float16*)(sm + S3OUT);
    _Float16* s4h = (_Float16*)(sm + S4OUT);

    const int t = threadIdx.x;
    const int b = blockIdx.x;

    {
        uint4* s4 = (uint4*)sm;
#pragma unroll
        for (int i = 0; i < 8; ++i) {
            const int k = t + i * 256;
            if (k < LDS_N / 4) s4[k] = make_uint4(0, 0, 0, 0);
        }
    }
    __syncthreads();

#pragma unroll
    for (int it = 0; it < 4; ++it) {
        const int i  = t + it * 256;
        const int xc = i & 3;
        const int yy = (i >> 2) & 7;
        const int zz = (i >> 5) & 7;
        const int cp = i >> 8;
        const uint2 v = *(const uint2*)&in[
            ((long)b * 4 + cp) * 512 + (zz * 8 + yy) * 8 + 2 * xc];
        uint* sp = &sm[S3IN + cp * 1200 + (zz + 1) * 120 + (yy + 1) * 12 +
                       3 + 2 * xc];
        sp[0] = v.x; sp[1] = v.y;
    }
    __syncthreads();

    // ---- L3: pos64 x cog4 (wave-uniform), 4 co per thread ----
    {
        const int pos = t & 63;
        const int cog = __builtin_amdgcn_readfirstlane(t >> 6);
        const int xp = pos & 3;
        const int yp = (pos >> 2) & 3;
        const int zp = pos >> 4;

        float acc[4][8];
#pragma unroll
        for (int oo = 0; oo < 4; ++oo)
#pragma unroll
            for (int p = 0; p < 8; ++p) acc[oo][p] = 0.f;

#pragma unroll 1
        for (int cp = 0; cp < 4; ++cp) {
            const uint* base = &sm[S3IN + cp * 1200 + 2 * zp * 120 +
                                   2 * yp * 12 + 2 * xp + 2];
#pragma unroll
            for (int dz = 0; dz < 4; ++dz) {
                half2_t v[4][4];
#pragma unroll
                for (int dy = 0; dy < 4; ++dy) {
                    const uint2 q0 = *(const uint2*)&base[dz * 120 + dy * 12];
                    const uint2 q1 = *(const uint2*)&base[dz * 120 + dy * 12 + 2];
                    v[dy][0] = as_h2(q0.x); v[dy][1] = as_h2(q0.y);
                    v[dy][2] = as_h2(q1.x); v[dy][3] = as_h2(q1.y);
                }
#pragma unroll
                for (int kz = 0; kz < 3; ++kz) {
                    const int pz = dz - kz;
                    if (pz >= 0 && pz < 2) {
#pragma unroll
                        for (int oo = 0; oo < 4; ++oo) {
                            const uint* wp = &wh3[((cog * 4 + oo) * 4 + cp) * 27 +
                                                  kz * 9];
#pragma unroll
                            for (int ky = 0; ky < 3; ++ky)
#pragma unroll
                                for (int kx = 0; kx < 3; ++kx) {
                                    const half2_t wv = as_h2(wp[ky * 3 + kx]);
#pragma unroll
                                    for (int py = 0; py < 2; ++py)
#pragma unroll
                                        for (int px = 0; px < 2; ++px)
                                            acc[oo][pz * 4 + py * 2 + px] =
                                                fdot2(v[py + ky][px + kx], wv,
                                                      acc[oo][pz * 4 + py * 2 + px]);
                                }
                        }
                    }
                }
            }
        }
        const int hbase = (((zp + 1) * 6 + (yp + 1)) * 6 + (xp + 1)) << 4;
#pragma unroll
        for (int oo = 0; oo < 4; ++oo) {
            const int co = cog * 4 + oo;
            float m = acc[oo][0];
#pragma unroll
            for (int p = 1; p < 8; ++p) m = fmaxf(m, acc[oo][p]);
            s3h[hbase + co] = (_Float16)lrelu(m + cb3[co]);
        }
    }
    __syncthreads();

    // ---- L4: pos8 x co32 ----
    {
        const int co = t >> 3;
        const int pos = t & 7;
        const int xp = pos & 1;
        const int yp = (pos >> 1) & 1;
        const int zp = pos >> 2;
        const uint* vbase = &sm[S3OUT + (((2 * zp * 6 + 2 * yp) * 6 + 2 * xp) << 3)];
        float acc[8];
#pragma unroll
        for (int p = 0; p < 8; ++p) acc[p] = 0.f;
#pragma unroll 1
        for (int c = 0; c < 8; ++c) {
            const uint* wp = &wh4[(co * 8 + c) * 27];
#pragma unroll
            for (int dz = 0; dz < 4; ++dz) {
                half2_t v[4][4];
#pragma unroll
                for (int dy = 0; dy < 4; ++dy)
#pragma unroll
                    for (int dx = 0; dx < 4; ++dx)
                        v[dy][dx] = as_h2(vbase[(((dz * 6 + dy) * 6 + dx) << 3) + c]);
#pragma unroll
                for (int kz = 0; kz < 3; ++kz) {
                    const int pz = dz - kz;
                    if (pz >= 0 && pz < 2) {
#pragma unroll
                        for (int ky = 0; ky < 3; ++ky)
#pragma unroll
                            for (int kx = 0; kx < 3; ++kx) {
                                const half2_t wv = as_h2(wp[kz * 9 + ky * 3 + kx]);
#pragma unroll
                                for (int py = 0; py < 2; ++py)
#pragma unroll
                                    for (int px = 0; px < 2; ++px)
                                        acc[pz * 4 + py * 2 + px] =
                                            fdot2(v[py + ky][px + kx], wv,
                                                  acc[pz * 4 + py * 2 + px]);
                            }
                    }
                }
            }
        }
        float m = acc[0];
#pragma unroll
        for (int p = 1; p < 8; ++p) m = fmaxf(m, acc[p]);
        s4h[((((zp + 1) * 4 + (yp + 1)) * 4 + (xp + 1)) << 5) + co] =
            (_Float16)lrelu(m + cb4[co]);
    }
    __syncthreads();

    // ---- L5: co64 x cq4 partials ----
    {
        const int co = t & 63;
        const int cq = __builtin_amdgcn_readfirstlane(t >> 6);
        float acc[8];
#pragma unroll
        for (int p = 0; p < 8; ++p) acc[p] = 0.f;
#pragma unroll 1
        for (int ci = 0; ci < 4; ++ci) {
            const int c = cq * 4 + ci;
            const uint* wp = &wh5[(co * 16 + c) * 27];
#pragma unroll
            for (int dz = 0; dz < 4; ++dz) {
                half2_t v[4][4];
#pragma unroll
                for (int dy = 0; dy < 4; ++dy)
#pragma unroll
                    for (int dx = 0; dx < 4; ++dx)
                        v[dy][dx] = as_h2(sm[S4OUT +
                            (((dz * 4 + dy) * 4 + dx) << 4) + c]);
#pragma unroll
                for (int kz = 0; kz < 3; ++kz) {
                    const int pz = dz - kz;
                    if (pz >= 0 && pz < 2) {
#pragma unroll
                        for (int ky = 0; ky < 3; ++ky)
#pragma unroll
                            for (int kx = 0; kx < 3; ++kx) {
                                const half2_t wv = as_h2(wp[kz * 9 + ky * 3 + kx]);
#pragma unroll
                                for (int py = 0; py < 2; ++py)
#pragma unroll
                                    for (int px = 0; px < 2; ++px)
                                        acc[pz * 4 + py * 2 + px] =
                                            fdot2(v[py + ky][px + kx], wv,
                                                  acc[pz * 4 + py * 2 + px]);
                            }
                    }
                }
            }
        }
#pragma unroll
        for (int p = 0; p < 8; ++p)
            smf[(cq * 64 + co) * 9 + p] = acc[p];
    }
    __syncthreads();

    if (t < 64) {
        float acc[8];
#pragma unroll
        for (int p = 0; p < 8; ++p)
            acc[p] = smf[t * 9 + p] + smf[(64 + t) * 9 + p] +
                     smf[(128 + t) * 9 + p] + smf[(192 + t) * 9 + p];
        float m = acc[0];
#pragma unroll
        for (int p = 1; p < 8; ++p) m = fmaxf(m, acc[p]);
        smf[FEAT + t] = lrelu(m + cb5[t]);
    }
    __syncthreads();

    if (t < 192) {
        const int j = t & 31;
        const int h = t >> 5;
        float s = fb1[h * 32 + j];
#pragma unroll
        for (int k = 0; k < 64; ++k)
            s += smf[FEAT + k] * W1[(h * 64 + k) * 32 + j];
        smf[H1O + h * 32 + j] = lrelu(s);
    }
    __syncthreads();

    if (t < 96) {
        const int j = t & 15;
        const int h = t >> 4;
        float s = fb2[h * 16 + j];
#pragma unroll
        for (int k = 0; k < 32; ++k)
            s += smf[H1O + h * 32 + k] * W2[(h * 32 + k) * 16 + j];
        smf[H2O + h * 16 + j] = lrelu(s);
    }
    __syncthreads();

    if (t < 24) {
        const int j = t & 3;
        const int h = t >> 2;
        float s = fb3[h * 4 + j];
#pragma unroll
        for (int k = 0; k < 16; ++k)
            s += smf[H2O + h * 16 + k] * W3[(h * 16 + k) * 4 + j];
        smf[H3O + h * 4 + j] = lrelu(s);
    }
    __syncthreads();

    if (t < 24) {
        const int q = t & 3;
        const int h = t >> 2;
        const float x0 = smf[H3O + h * 4 + 0];
        const float x1 = smf[H3O + h * 4 + 1];
        const float x2 = smf[H3O + h * 4 + 2];
        const float x3 = smf[H3O + h * 4 + 3];
        const float inv = 1.f / sqrtf(x0 * x0 + x1 * x1 + x2 * x2 + x3 * x3);
        out[(b * 6 + h) * 4 + q] = smf[H3O + h * 4 + q] * inv;
    }
}

// ---------------------------------------------------------------------------
// Weight pre-pack: fp32 [CO][CI][27] -> half2 [CO][CI/2][27] (pairs over ci).
// ---------------------------------------------------------------------------
__device__ __forceinline__ void pack_one(int i, const float* w, uint* h,
                                         int CO, int CI)
{
    const int CIH = CI / 2;
    const int n = CO * CIH * 27;
    if (i < n) {
        const int tap = i % 27;
        const int r   = i / 27;
        const int cp  = r % CIH;
        const int co  = r / CIH;
        const float* s = w + ((co * CI + 2 * cp) * 27 + tap);
        union { uint u; half2_t v; } c;
        c.v.x = (_Float16)s[0];
        c.v.y = (_Float16)s[27];
        h[i] = c.u;
    }
}

__global__ __launch_bounds__(256) void pack_weights(
    const float* w2, const float* w3, const float* w4, const float* w5,
    uint* h2, uint* h3, uint* h4, uint* h5)
{
    const int i = blockIdx.x * 256 + threadIdx.x;
    pack_one(i, w2, h2, 8, 4);
    pack_one(i, w3, h3, 16, 8);
    pack_one(i, w4, h4, 32, 16);
    pack_one(i, w5, h5, 64, 32);
}

extern "C" void kernel_launch(void* const* d_in, const int* in_sizes, int n_in,
                              void* d_out, int out_size, void* d_ws, size_t ws_size,
                              hipStream_t stream)
{
    const float* voxel = (const float*)d_in[0];
    const float* cw1 = (const float*)d_in[1];  const float* cb1 = (const float*)d_in[2];
    const float* cw2 = (const float*)d_in[3];  const float* cb2 = (const float*)d_in[4];
    const float* cw3 = (const float*)d_in[5];  const float* cb3 = (const float*)d_in[6];
    const float* cw4 = (const float*)d_in[7];  const float* cb4 = (const float*)d_in[8];
    const float* cw5 = (const float*)d_in[9];  const float* cb5 = (const float*)d_in[10];
    const float* W1  = (const float*)d_in[11]; const float* b1  = (const float*)d_in[12];
    const float* W2  = (const float*)d_in[13]; const float* b2  = (const float*)d_in[14];
    const float* W3  = (const float*)d_in[15]; const float* b3  = (const float*)d_in[16];
    float* out = (float*)d_out;

    const int B = 1024;
    uint* buf1h = (uint*)d_ws;                 // [1024][2][16^3]  8388608 w
    uint* buf2h = buf1h + 8388608;             // [1024][4][8^3]   2097152 w
    uint* wh2   = buf2h + 2097152;             // 432
    uint* wh3   = wh2 + 432;                   // 1728
    uint* wh4   = wh3 + 1728;                  // 6912
    uint* wh5   = wh4 + 6912;                  // 27648

    pack_weights<<<108, 256, 0, stream>>>(cw2, cw3, cw4, cw5, wh2, wh3, wh4, wh5);

    // L1: 1->4, 32^3->16^3 (fp32, packed v_pk_fma_f32 over px pairs)
    conv_pool_f32h<1, 4, 32, 2, 2, 4, 1><<<1024 * 8, 256, 0, stream>>>(
        voxel, cw1, cb1, (half2_t*)buf1h, B);
    // L2: CIH=2, 16^3->8^3 (dot2, BPB=1 CPT=2: 19KB LDS, 8 blk/CU, merged-zi)
    conv_pool_h2<2, 8, 16, 2, 2, 2, 1><<<1024 * 4, 256, 0, stream>>>(
        (const half2_t*)buf1h, wh2, cb2, (half2_t*)buf2h, B);
    // L3+L4+L5+FC fused: 1 batch/block (unchanged)
    tail_fused2<<<1024, 256, 0, stream>>>(
        buf2h, wh3, wh4, wh5, cb3, cb4, cb5,
        W1, b1, W2, b2, W3, b3, out);
}

// Round 9
// 374.580 us; speedup vs baseline: 3.4936x; 1.0095x over previous
//
#include <hip/hip_runtime.h>
#include <math.h>

#define NEG_SLOPE 0.2f

typedef _Float16 half2_t __attribute__((ext_vector_type(2)));

__device__ __forceinline__ float lrelu(float x) {
    return fmaxf(x, NEG_SLOPE * x);
}

__device__ __forceinline__ float fdot2(half2_t a, half2_t b, float c) {
#if __has_builtin(__builtin_amdgcn_fdot2)
    return __builtin_amdgcn_fdot2(a, b, c, false);
#else
    return c + (float)a.x * (float)b.x + (float)a.y * (float)b.y;
#endif
}

__device__ __forceinline__ half2_t as_h2(uint u) {
    union { uint u; half2_t h; } c; c.u = u; return c.h;
}

typedef float v2f __attribute__((ext_vector_type(2)));

constexpr int clog2(int n) { return (n <= 1) ? 0 : 1 + clog2(n / 2); }

// ---------------------------------------------------------------------------
// Layer 1 (fp32, CI=1). r8 FROZEN: packed v_pk_fma over px pairs.
// Measured r8: 103.5us, VALU-busy halved vs scalar, WRITE_SIZE == output.
// ---------------------------------------------------------------------------
template<int CI, int CO, int S, int ZT, int PZT, int CPT, int BPB>
__global__ __launch_bounds__(256, 4) void conv_pool_f32h(
    const float* __restrict__ in,   // [B, CI, S,S,S]
    const float* __restrict__ w,    // [CO, CI, 3,3,3]
    const float* __restrict__ bias, // [CO]
    half2_t* __restrict__ out,      // [B, CO/2, SP^3] co-pair packed
    int B)
{
    constexpr int SP    = S / 2;
    constexpr int ZD    = 2 * ZT + 2;
    constexpr int YS    = S + 2;
    constexpr int XOFF  = 5;
    constexpr int XR    = S + 8;
    constexpr int PLANE = YS * XR;
    constexpr int NPAIR = BPB * CI * ZD;
    constexpr int LDS_N = NPAIR * PLANE;
    constexpr int NOG   = CO / CPT;
    constexpr int NZB   = ZT / PZT;
    constexpr int NPOS  = NZB * SP * SP;
    constexpr int NSLAB = SP / ZT;
    static_assert(BPB * NOG * NPOS == 256, "thread mapping must cover block");
    static_assert((LDS_N & 3) == 0, "float4 zero");
    static_assert((CPT & 1) == 0, "pack pairs");

    __shared__ __align__(16) float sm[LDS_N];

    const int t     = threadIdx.x;
    const int zslab = blockIdx.x & (NSLAB - 1);
    const int b0    = (blockIdx.x >> clog2(NSLAB)) * BPB;
    const int zp0   = zslab * ZT;
    const int gz0   = 2 * zp0 - 1;

    {   // Phase A: zero LDS
        float4* s4 = (float4*)sm;
        constexpr int N4 = LDS_N / 4;
#pragma unroll
        for (int i = 0; i < (N4 + 255) / 256; ++i) {
            const int k = t + i * 256;
            if (k < N4) s4[k] = make_float4(0.f, 0.f, 0.f, 0.f);
        }
    }
    __syncthreads();

    {   // Phase B: interior rows, float4 loads
        constexpr int CHUNKS = S / 4;
        constexpr int PJOBS  = S * CHUNKS;
        constexpr int PPI    = 256 / PJOBS;
        constexpr int FITER  = NPAIR / PPI;
        static_assert(FITER * PPI == NPAIR, "fill covers planes exactly");
        const int idx  = t & (PJOBS - 1);
        const int poff = t >> clog2(PJOBS);
        const int cc   = idx & (CHUNKS - 1);
        const int yy   = idx >> clog2(CHUNKS);
#pragma unroll
        for (int it = 0; it < FITER; ++it) {
            const int plane = it * PPI + poff;
            const int z     = plane % ZD;
            const int bci   = plane / ZD;
            const int gz    = gz0 + z;
            if ((unsigned)gz < (unsigned)S) {
                const float4 v = *(const float4*)&in[
                    ((long)(b0 * CI + bci) * S + gz) * (S * S) + yy * S + 4 * cc];
                float* sp = &sm[(plane * YS + (yy + 1)) * XR + XOFF + 4 * cc];
                sp[0] = v.x; sp[1] = v.y; sp[2] = v.z; sp[3] = v.w;
            }
        }
    }
    __syncthreads();

    const int pos = t & (NPOS - 1);
    const int og  = __builtin_amdgcn_readfirstlane(
                        (t >> clog2(NPOS)) & (NOG - 1));      // wave-uniform
    const int bl  = __builtin_amdgcn_readfirstlane(
                        t >> clog2(NPOS * NOG));              // wave-uniform
    const int xp  = pos & (SP - 1);
    const int yp  = (pos >> clog2(SP)) & (SP - 1);
    const int zb  = pos >> (2 * clog2(SP));

#pragma unroll 1
    for (int zi = 0; zi < PZT; ++zi) {
        const int zl = zb * PZT + zi;
#pragma unroll 1
        for (int oh = 0; oh < CPT; oh += 2) {
            // acc[oo][pz*2+py], vector lane = px in {0,1}
            v2f acc[2][4];
#pragma unroll
            for (int oo = 0; oo < 2; ++oo)
#pragma unroll
                for (int j = 0; j < 4; ++j) { acc[oo][j].x = 0.f; acc[oo][j].y = 0.f; }

#pragma unroll 1
            for (int ci = 0; ci < CI; ++ci) {
                const float* sp_ = &sm[((bl * CI + ci) * ZD + 2 * zl) * PLANE +
                                       (2 * yp) * XR + 2 * xp + (XOFF - 1)];
#pragma unroll
                for (int dz = 0; dz < 4; ++dz) {
                    // per-row pair registers: (x0,x1) (x1,x2) (x2,x3)
                    v2f p01[4], p12[4], p23[4];
#pragma unroll
                    for (int dy = 0; dy < 4; ++dy) {
                        const float2 q0 = *(const float2*)&sp_[dz * PLANE + dy * XR];
                        const float2 q1 = *(const float2*)&sp_[dz * PLANE + dy * XR + 2];
                        p01[dy].x = q0.x; p01[dy].y = q0.y;
                        p12[dy].x = q0.y; p12[dy].y = q1.x;
                        p23[dy].x = q1.x; p23[dy].y = q1.y;
                    }
#pragma unroll
                    for (int kz = 0; kz < 3; ++kz) {
                        const int pz = dz - kz;
                        if (pz >= 0 && pz < 2) {
#pragma unroll
                            for (int oo = 0; oo < 2; ++oo) {
                                const float* wp = w +
                                    (long)((og * CPT + oh + oo) * CI + ci) * 27 +
                                    kz * 9;
#pragma unroll
                                for (int ky = 0; ky < 3; ++ky) {
                                    const float w0 = wp[ky * 3 + 0];
                                    const float w1 = wp[ky * 3 + 1];
                                    const float w2 = wp[ky * 3 + 2];
#pragma unroll
                                    for (int py = 0; py < 2; ++py) {
                                        const int r = py + ky;
                                        v2f a = acc[oo][pz * 2 + py];
                                        a += p01[r] * w0;   // kx=0 (both px)
                                        a += p12[r] * w1;   // kx=1
                                        a += p23[r] * w2;   // kx=2
                                        acc[oo][pz * 2 + py] = a;
                                    }
                                }
                            }
                        }
                    }
                }
            }

            const int o = og * CPT + oh;
            // maxpool: same comparison order as the scalar acc[0..7] walk
            float m0 = acc[0][0].x, m1 = acc[1][0].x;
            m0 = fmaxf(m0, acc[0][0].y); m1 = fmaxf(m1, acc[1][0].y);
#pragma unroll
            for (int j = 1; j < 4; ++j) {
                m0 = fmaxf(m0, acc[0][j].x); m0 = fmaxf(m0, acc[0][j].y);
                m1 = fmaxf(m1, acc[1][j].x); m1 = fmaxf(m1, acc[1][j].y);
            }
            half2_t hv;
            hv.x = (_Float16)lrelu(m0 + bias[o]);
            hv.y = (_Float16)lrelu(m1 + bias[o + 1]);
            out[(long)((b0 + bl) * (CO / 2) + (o >> 1)) * (SP * SP * SP) +
                ((zp0 + zl) * SP + yp) * SP + xp] = hv;
        }
    }
}

// ---------------------------------------------------------------------------
// Layer 2. r9: zi-SPLIT passes (revert r4's merged-zi, which was never
// isolated): acc[CPT=2][8] = 16 floats per pass -> below the 32-float AGPR
// exile threshold identified on L1 (r2: 3 VALU/FMA signature). Keeps r4's
// occupancy config (BPB=1, 19KB LDS, 8 blk/CU). Per-acc-element tap order
// (cp asc, dz asc, kz asc) unchanged -> bitwise identical.
// ---------------------------------------------------------------------------
template<int CIH, int CO, int S, int ZT, int PZT, int CPT, int BPB>
__global__ __launch_bounds__(256, 6) void conv_pool_h2(
    const half2_t* __restrict__ in,  // [B, CIH, S,S,S]
    const uint*   __restrict__ wh,   // [CO, CIH, 27] packed pairs
    const float*  __restrict__ bias, // [CO]
    half2_t* __restrict__ out,       // [B, CO/2, SP^3]
    int B)
{
    constexpr int SP    = S / 2;
    constexpr int ZD    = 2 * ZT + 2;
    constexpr int YS    = S + 2;
    constexpr int XOFF  = 3;
    constexpr int XR    = S + 6;
    constexpr int PLANE = YS * XR;
    constexpr int NPAIR = BPB * CIH * ZD;
    constexpr int LDS_N = NPAIR * PLANE;
    constexpr int NOG   = CO / CPT;
    constexpr int NZB   = ZT / PZT;
    constexpr int NPOS  = NZB * SP * SP;
    constexpr int NSLAB = SP / ZT;
    static_assert(BPB * NOG * NPOS == 256, "thread mapping must cover block");
    static_assert((LDS_N & 3) == 0, "uint4 zero");
    static_assert((CPT & 1) == 0, "pack pairs");

    __shared__ __align__(16) uint sm[LDS_N];
    const uint* inu = (const uint*)in;

    const int t     = threadIdx.x;
    const int zslab = blockIdx.x & (NSLAB - 1);
    const int b0    = (blockIdx.x >> clog2(NSLAB)) * BPB;
    const int zp0   = zslab * ZT;
    const int gz0   = 2 * zp0 - 1;

    {   // Phase A: zero LDS
        uint4* s4 = (uint4*)sm;
        constexpr int N4 = LDS_N / 4;
#pragma unroll
        for (int i = 0; i < (N4 + 255) / 256; ++i) {
            const int k = t + i * 256;
            if (k < N4) s4[k] = make_uint4(0, 0, 0, 0);
        }
    }
    __syncthreads();

    {   // Phase B: interior rows, uint2 global loads
        constexpr int CH    = S / 2;
        constexpr int PJOBS = S * CH;
        constexpr int ITERS = NPAIR * PJOBS / 256;
        static_assert(ITERS * 256 == NPAIR * PJOBS, "exact fill");
#pragma unroll
        for (int it = 0; it < ITERS; ++it) {
            const int i     = t + it * 256;
            const int idx   = i & (PJOBS - 1);
            const int plane = i >> clog2(PJOBS);
            const int cc    = idx & (CH - 1);
            const int yy    = idx >> clog2(CH);
            const int z     = plane % ZD;
            const int bci   = plane / ZD;
            const int gz    = gz0 + z;
            if ((unsigned)gz < (unsigned)S) {
                const uint2 v = *(const uint2*)&inu[
                    ((long)(b0 * CIH + bci) * S + gz) * (S * S) + yy * S + 2 * cc];
                uint* sp = &sm[(plane * YS + yy + 1) * XR + XOFF + 2 * cc];
                sp[0] = v.x; sp[1] = v.y;
            }
        }
    }
    __syncthreads();

    const int pos = t & (NPOS - 1);
    const int og  = __builtin_amdgcn_readfirstlane(
                        (t >> clog2(NPOS)) & (NOG - 1));       // wave-uniform
    const int bl  = __builtin_amdgcn_readfirstlane(
                        t >> clog2(NPOS * NOG));               // wave-uniform
    const int xp  = pos & (SP - 1);
    const int yp  = (pos >> clog2(SP)) & (SP - 1);
    const int zb  = pos >> (2 * clog2(SP));

#pragma unroll 1
    for (int zi = 0; zi < PZT; ++zi) {
        const int zl = zb * PZT + zi;
        float acc[CPT][8];
#pragma unroll
        for (int oo = 0; oo < CPT; ++oo)
#pragma unroll
            for (int p = 0; p < 8; ++p) acc[oo][p] = 0.f;

#pragma unroll 1
        for (int cp = 0; cp < CIH; ++cp) {
            const uint* sp_ = &sm[((bl * CIH + cp) * ZD + 2 * zl) * PLANE +
                                  (2 * yp) * XR + 2 * xp + (XOFF - 1)]; // even
#pragma unroll
            for (int dz = 0; dz < 4; ++dz) {
                half2_t v[4][4];
#pragma unroll
                for (int dy = 0; dy < 4; ++dy) {
                    const uint2 q0 = *(const uint2*)&sp_[dz * PLANE + dy * XR];
                    const uint2 q1 = *(const uint2*)&sp_[dz * PLANE + dy * XR + 2];
                    v[dy][0] = as_h2(q0.x); v[dy][1] = as_h2(q0.y);
                    v[dy][2] = as_h2(q1.x); v[dy][3] = as_h2(q1.y);
                }
#pragma unroll
                for (int kz = 0; kz < 3; ++kz) {
                    const int pz = dz - kz;
                    if (pz >= 0 && pz < 2) {
#pragma unroll
                        for (int oo = 0; oo < CPT; ++oo) {
                            const uint* wp = wh +
                                (long)((og * CPT + oo) * CIH + cp) * 27 + kz * 9;
#pragma unroll
                            for (int ky = 0; ky < 3; ++ky)
#pragma unroll
                                for (int kx = 0; kx < 3; ++kx) {
                                    const half2_t wv = as_h2(wp[ky * 3 + kx]);
#pragma unroll
                                    for (int py = 0; py < 2; ++py)
#pragma unroll
                                        for (int px = 0; px < 2; ++px)
                                            acc[oo][pz * 4 + py * 2 + px] =
                                                fdot2(v[py + ky][px + kx], wv,
                                                      acc[oo][pz * 4 + py * 2 + px]);
                                }
                        }
                    }
                }
            }
        }

#pragma unroll
        for (int oo = 0; oo < CPT; oo += 2) {
            const int o = og * CPT + oo;
            float m0 = acc[oo][0], m1 = acc[oo + 1][0];
#pragma unroll
            for (int p = 1; p < 8; ++p) {
                m0 = fmaxf(m0, acc[oo][p]);
                m1 = fmaxf(m1, acc[oo + 1][p]);
            }
            half2_t hv;
            hv.x = (_Float16)lrelu(m0 + bias[o]);
            hv.y = (_Float16)lrelu(m1 + bias[o + 1]);
            out[(long)((b0 + bl) * (CO / 2) + (o >> 1)) * (SP * SP * SP) +
                ((zp0 + zl) * SP + yp) * SP + xp] = hv;
        }
    }
}

// ---------------------------------------------------------------------------
// Fused tail. r9: L3 co-split (4 co -> 2 passes of 2, acc[2][8] = 16 floats,
// below the AGPR exile threshold). L4/L5 acc[8] already small. Tap order per
// acc element unchanged (cp asc, dz asc, kz asc) -> bitwise identical.
// ---------------------------------------------------------------------------
__global__ __launch_bounds__(256, 4) void tail_fused2(
    const uint*  __restrict__ in,   // buf2h [B][4][8^3] half2 words
    const uint*  __restrict__ wh3,  // [16][4][27]
    const uint*  __restrict__ wh4,  // [32][8][27]
    const uint*  __restrict__ wh5,  // [64][16][27]
    const float* __restrict__ cb3, const float* __restrict__ cb4,
    const float* __restrict__ cb5,
    const float* __restrict__ W1, const float* __restrict__ fb1,
    const float* __restrict__ W2, const float* __restrict__ fb2,
    const float* __restrict__ W3, const float* __restrict__ fb3,
    float* __restrict__ out)        // [B,6,4]
{
    constexpr int S3IN  = 0;
    constexpr int S3OUT = 4800;
    constexpr int S4OUT = 6528;
    constexpr int FEAT  = 7552;
    constexpr int H1O   = 7616;
    constexpr int H2O   = 7808;
    constexpr int H3O   = 7904;
    constexpr int LDS_N = 7936;

    __shared__ __align__(16) uint sm[LDS_N];
    float* smf = (float*)sm;
    _Float16* s3h = (_Float16*)(sm + S3OUT);
    _Float16* s4h = (_Float16*)(sm + S4OUT);

    const int t = threadIdx.x;
    const int b = blockIdx.x;

    {
        uint4* s4 = (uint4*)sm;
#pragma unroll
        for (int i = 0; i < 8; ++i) {
            const int k = t + i * 256;
            if (k < LDS_N / 4) s4[k] = make_uint4(0, 0, 0, 0);
        }
    }
    __syncthreads();

#pragma unroll
    for (int it = 0; it < 4; ++it) {
        const int i  = t + it * 256;
        const int xc = i & 3;
        const int yy = (i >> 2) & 7;
        const int zz = (i >> 5) & 7;
        const int cp = i >> 8;
        const uint2 v = *(const uint2*)&in[
            ((long)b * 4 + cp) * 512 + (zz * 8 + yy) * 8 + 2 * xc];
        uint* sp = &sm[S3IN + cp * 1200 + (zz + 1) * 120 + (yy + 1) * 12 +
                       3 + 2 * xc];
        sp[0] = v.x; sp[1] = v.y;
    }
    __syncthreads();

    // ---- L3: pos64 x cog4 (wave-uniform), co-split 2+2 per thread ----
    {
        const int pos = t & 63;
        const int cog = __builtin_amdgcn_readfirstlane(t >> 6);
        const int xp = pos & 3;
        const int yp = (pos >> 2) & 3;
        const int zp = pos >> 4;
        const int hbase = (((zp + 1) * 6 + (yp + 1)) * 6 + (xp + 1)) << 4;

#pragma unroll 1
        for (int oh = 0; oh < 4; oh += 2) {
            float acc[2][8];
#pragma unroll
            for (int oo = 0; oo < 2; ++oo)
#pragma unroll
                for (int p = 0; p < 8; ++p) acc[oo][p] = 0.f;

#pragma unroll 1
            for (int cp = 0; cp < 4; ++cp) {
                const uint* base = &sm[S3IN + cp * 1200 + 2 * zp * 120 +
                                       2 * yp * 12 + 2 * xp + 2];
#pragma unroll
                for (int dz = 0; dz < 4; ++dz) {
                    half2_t v[4][4];
#pragma unroll
                    for (int dy = 0; dy < 4; ++dy) {
                        const uint2 q0 = *(const uint2*)&base[dz * 120 + dy * 12];
                        const uint2 q1 = *(const uint2*)&base[dz * 120 + dy * 12 + 2];
                        v[dy][0] = as_h2(q0.x); v[dy][1] = as_h2(q0.y);
                        v[dy][2] = as_h2(q1.x); v[dy][3] = as_h2(q1.y);
                    }
#pragma unroll
                    for (int kz = 0; kz < 3; ++kz) {
                        const int pz = dz - kz;
                        if (pz >= 0 && pz < 2) {
#pragma unroll
                            for (int oo = 0; oo < 2; ++oo) {
                                const uint* wp = &wh3[
                                    ((cog * 4 + oh + oo) * 4 + cp) * 27 + kz * 9];
#pragma unroll
                                for (int ky = 0; ky < 3; ++ky)
#pragma unroll
                                    for (int kx = 0; kx < 3; ++kx) {
                                        const half2_t wv = as_h2(wp[ky * 3 + kx]);
#pragma unroll
                                        for (int py = 0; py < 2; ++py)
#pragma unroll
                                            for (int px = 0; px < 2; ++px)
                                                acc[oo][pz * 4 + py * 2 + px] =
                                                    fdot2(v[py + ky][px + kx], wv,
                                                          acc[oo][pz * 4 + py * 2 + px]);
                                    }
                            }
                        }
                    }
                }
            }
#pragma unroll
            for (int oo = 0; oo < 2; ++oo) {
                const int co = cog * 4 + oh + oo;
                float m = acc[oo][0];
#pragma unroll
                for (int p = 1; p < 8; ++p) m = fmaxf(m, acc[oo][p]);
                s3h[hbase + co] = (_Float16)lrelu(m + cb3[co]);
            }
        }
    }
    __syncthreads();

    // ---- L4: pos8 x co32 ----
    {
        const int co = t >> 3;
        const int pos = t & 7;
        const int xp = pos & 1;
        const int yp = (pos >> 1) & 1;
        const int zp = pos >> 2;
        const uint* vbase = &sm[S3OUT + (((2 * zp * 6 + 2 * yp) * 6 + 2 * xp) << 3)];
        float acc[8];
#pragma unroll
        for (int p = 0; p < 8; ++p) acc[p] = 0.f;
#pragma unroll 1
        for (int c = 0; c < 8; ++c) {
            const uint* wp = &wh4[(co * 8 + c) * 27];
#pragma unroll
            for (int dz = 0; dz < 4; ++dz) {
                half2_t v[4][4];
#pragma unroll
                for (int dy = 0; dy < 4; ++dy)
#pragma unroll
                    for (int dx = 0; dx < 4; ++dx)
                        v[dy][dx] = as_h2(vbase[(((dz * 6 + dy) * 6 + dx) << 3) + c]);
#pragma unroll
                for (int kz = 0; kz < 3; ++kz) {
                    const int pz = dz - kz;
                    if (pz >= 0 && pz < 2) {
#pragma unroll
                        for (int ky = 0; ky < 3; ++ky)
#pragma unroll
                            for (int kx = 0; kx < 3; ++kx) {
                                const half2_t wv = as_h2(wp[kz * 9 + ky * 3 + kx]);
#pragma unroll
                                for (int py = 0; py < 2; ++py)
#pragma unroll
                                    for (int px = 0; px < 2; ++px)
                                        acc[pz * 4 + py * 2 + px] =
                                            fdot2(v[py + ky][px + kx], wv,
                                                  acc[pz * 4 + py * 2 + px]);
                            }
                    }
                }
            }
        }
        float m = acc[0];
#pragma unroll
        for (int p = 1; p < 8; ++p) m = fmaxf(m, acc[p]);
        s4h[((((zp + 1) * 4 + (yp + 1)) * 4 + (xp + 1)) << 5) + co] =
            (_Float16)lrelu(m + cb4[co]);
    }
    __syncthreads();

    // ---- L5: co64 x cq4 partials ----
    {
        const int co = t & 63;
        const int cq = __builtin_amdgcn_readfirstlane(t >> 6);
        float acc[8];
#pragma unroll
        for (int p = 0; p < 8; ++p) acc[p] = 0.f;
#pragma unroll 1
        for (int ci = 0; ci < 4; ++ci) {
            const int c = cq * 4 + ci;
            const uint* wp = &wh5[(co * 16 + c) * 27];
#pragma unroll
            for (int dz = 0; dz < 4; ++dz) {
                half2_t v[4][4];
#pragma unroll
                for (int dy = 0; dy < 4; ++dy)
#pragma unroll
                    for (int dx = 0; dx < 4; ++dx)
                        v[dy][dx] = as_h2(sm[S4OUT +
                            (((dz * 4 + dy) * 4 + dx) << 4) + c]);
#pragma unroll
                for (int kz = 0; kz < 3; ++kz) {
                    const int pz = dz - kz;
                    if (pz >= 0 && pz < 2) {
#pragma unroll
                        for (int ky = 0; ky < 3; ++ky)
#pragma unroll
                            for (int kx = 0; kx < 3; ++kx) {
                                const half2_t wv = as_h2(wp[kz * 9 + ky * 3 + kx]);
#pragma unroll
                                for (int py = 0; py < 2; ++py)
#pragma unroll
                                    for (int px = 0; px < 2; ++px)
                                        acc[pz * 4 + py * 2 + px] =
                                            fdot2(v[py + ky][px + kx], wv,
                                                  acc[pz * 4 + py * 2 + px]);
                            }
                    }
                }
            }
        }
#pragma unroll
        for (int p = 0; p < 8; ++p)
            smf[(cq * 64 + co) * 9 + p] = acc[p];
    }
    __syncthreads();

    if (t < 64) {
        float acc[8];
#pragma unroll
        for (int p = 0; p < 8; ++p)
            acc[p] = smf[t * 9 + p] + smf[(64 + t) * 9 + p] +
                     smf[(128 + t) * 9 + p] + smf[(192 + t) * 9 + p];
        float m = acc[0];
#pragma unroll
        for (int p = 1; p < 8; ++p) m = fmaxf(m, acc[p]);
        smf[FEAT + t] = lrelu(m + cb5[t]);
    }
    __syncthreads();

    if (t < 192) {
        const int j = t & 31;
        const int h = t >> 5;
        float s = fb1[h * 32 + j];
#pragma unroll
        for (int k = 0; k < 64; ++k)
            s += smf[FEAT + k] * W1[(h * 64 + k) * 32 + j];
        smf[H1O + h * 32 + j] = lrelu(s);
    }
    __syncthreads();

    if (t < 96) {
        const int j = t & 15;
        const int h = t >> 4;
        float s = fb2[h * 16 + j];
#pragma unroll
        for (int k = 0; k < 32; ++k)
            s += smf[H1O + h * 32 + k] * W2[(h * 32 + k) * 16 + j];
        smf[H2O + h * 16 + j] = lrelu(s);
    }
    __syncthreads();

    if (t < 24) {
        const int j = t & 3;
        const int h = t >> 2;
        float s = fb3[h * 4 + j];
#pragma unroll
        for (int k = 0; k < 16; ++k)
            s += smf[H2O + h * 16 + k] * W3[(h * 16 + k) * 4 + j];
        smf[H3O + h * 4 + j] = lrelu(s);
    }
    __syncthreads();

    if (t < 24) {
        const int q = t & 3;
        const int h = t >> 2;
        const float x0 = smf[H3O + h * 4 + 0];
        const float x1 = smf[H3O + h * 4 + 1];
        const float x2 = smf[H3O + h * 4 + 2];
        const float x3 = smf[H3O + h * 4 + 3];
        const float inv = 1.f / sqrtf(x0 * x0 + x1 * x1 + x2 * x2 + x3 * x3);
        out[(b * 6 + h) * 4 + q] = smf[H3O + h * 4 + q] * inv;
    }
}

// ---------------------------------------------------------------------------
// Weight pre-pack: fp32 [CO][CI][27] -> half2 [CO][CI/2][27] (pairs over ci).
// ---------------------------------------------------------------------------
__device__ __forceinline__ void pack_one(int i, const float* w, uint* h,
                                         int CO, int CI)
{
    const int CIH = CI / 2;
    const int n = CO * CIH * 27;
    if (i < n) {
        const int tap = i % 27;
        const int r   = i / 27;
        const int cp  = r % CIH;
        const int co  = r / CIH;
        const float* s = w + ((co * CI + 2 * cp) * 27 + tap);
        union { uint u; half2_t v; } c;
        c.v.x = (_Float16)s[0];
        c.v.y = (_Float16)s[27];
        h[i] = c.u;
    }
}

__global__ __launch_bounds__(256) void pack_weights(
    const float* w2, const float* w3, const float* w4, const float* w5,
    uint* h2, uint* h3, uint* h4, uint* h5)
{
    const int i = blockIdx.x * 256 + threadIdx.x;
    pack_one(i, w2, h2, 8, 4);
    pack_one(i, w3, h3, 16, 8);
    pack_one(i, w4, h4, 32, 16);
    pack_one(i, w5, h5, 64, 32);
}

extern "C" void kernel_launch(void* const* d_in, const int* in_sizes, int n_in,
                              void* d_out, int out_size, void* d_ws, size_t ws_size,
                              hipStream_t stream)
{
    const float* voxel = (const float*)d_in[0];
    const float* cw1 = (const float*)d_in[1];  const float* cb1 = (const float*)d_in[2];
    const float* cw2 = (const float*)d_in[3];  const float* cb2 = (const float*)d_in[4];
    const float* cw3 = (const float*)d_in[5];  const float* cb3 = (const float*)d_in[6];
    const float* cw4 = (const float*)d_in[7];  const float* cb4 = (const float*)d_in[8];
    const float* cw5 = (const float*)d_in[9];  const float* cb5 = (const float*)d_in[10];
    const float* W1  = (const float*)d_in[11]; const float* b1  = (const float*)d_in[12];
    const float* W2  = (const float*)d_in[13]; const float* b2  = (const float*)d_in[14];
    const float* W3  = (const float*)d_in[15]; const float* b3  = (const float*)d_in[16];
    float* out = (float*)d_out;

    const int B = 1024;
    uint* buf1h = (uint*)d_ws;                 // [1024][2][16^3]  8388608 w
    uint* buf2h = buf1h + 8388608;             // [1024][4][8^3]   2097152 w
    uint* wh2   = buf2h + 2097152;             // 432
    uint* wh3   = wh2 + 432;                   // 1728
    uint* wh4   = wh3 + 1728;                  // 6912
    uint* wh5   = wh4 + 6912;                  // 27648

    pack_weights<<<108, 256, 0, stream>>>(cw2, cw3, cw4, cw5, wh2, wh3, wh4, wh5);

    // L1: 1->4, 32^3->16^3 (fp32, packed v_pk_fma over px pairs) [r8 frozen]
    conv_pool_f32h<1, 4, 32, 2, 2, 4, 1><<<1024 * 8, 256, 0, stream>>>(
        voxel, cw1, cb1, (half2_t*)buf1h, B);
    // L2: CIH=2, 16^3->8^3 (dot2, zi-split passes, acc 16 floats)
    conv_pool_h2<2, 8, 16, 2, 2, 2, 1><<<1024 * 4, 256, 0, stream>>>(
        (const half2_t*)buf1h, wh2, cb2, (half2_t*)buf2h, B);
    // L3+L4+L5+FC fused: 1 batch/block (L3 co-split 2+2)
    tail_fused2<<<1024, 256, 0, stream>>>(
        buf2h, wh3, wh4, wh5, cb3, cb4, cb5,
        W1, b1, W2, b2, W3, b3, out);
}